// Round 1
// baseline (2981.916 us; speedup 1.0000x reference)
//
#include <hip/hip_runtime.h>
#include <math.h>

#define TT 2048
#define NE 256
#define NHEAD 16

// ---------------- block reduce (256 threads) ----------------
__device__ __forceinline__ float blk_sum(float v, float* red, int tid) {
#pragma unroll
  for (int off = 32; off > 0; off >>= 1) v += __shfl_down(v, off, 64);
  __syncthreads();
  if ((tid & 63) == 0) red[tid >> 6] = v;
  __syncthreads();
  return red[0] + red[1] + red[2] + red[3];
}

// ---------------- 1. logmap ----------------
__global__ __launch_bounds__(256) void logmap_kernel(const float* __restrict__ x,
                                                     float* __restrict__ xh) {
  __shared__ float red[4];
  int row = blockIdx.x, tid = threadIdx.x;
  int t = row & (TT - 1);
  float uv = x[row * NE + tid];
  float rv = (t == 0) ? 0.f : x[row * NE - NE + tid];
  float xn2 = blk_sum(rv * rv, red, tid);
  float un2 = blk_sum(uv * uv, red, tid);
  float ip  = blk_sum(-rv * uv, red, tid);
  float den = 1.f + 2.f * ip + xn2 * un2;
  float mob = ((1.f + 2.f * ip + un2) * (-rv) + (1.f - xn2) * uv) / den;
  float an2 = blk_sum(mob * mob, red, tid);
  float an = sqrtf(an2);
  float cf = 1.f + xn2;
  float arg = fminf(sqrtf(an), 0.999f);
  xh[row * NE + tid] = cf * atanhf(arg) * mob / an;
}

// ---------------- 2. nq = rmsnorm(xh @ W_cq) ----------------
__global__ __launch_bounds__(128) void nq_kernel(const float* __restrict__ xh,
                                                 const float* __restrict__ W_cq,
                                                 const float* __restrict__ qnw,
                                                 float* __restrict__ nq) {
  int row = blockIdx.x, tid = threadIdx.x;  // 128 thr
  __shared__ float xr[256];
  __shared__ float red[128];
  xr[tid] = xh[row * 256 + tid];
  xr[tid + 128] = xh[row * 256 + tid + 128];
  __syncthreads();
  float acc = 0.f;
  if (tid < 96) {
    const float* wp = W_cq + tid;
#pragma unroll 4
    for (int k = 0; k < 256; ++k) acc += xr[k] * wp[k * 96];
  }
  red[tid] = (tid < 96) ? acc * acc : 0.f;
  __syncthreads();
  for (int s = 64; s > 0; s >>= 1) {
    if (tid < s) red[tid] += red[tid + s];
    __syncthreads();
  }
  float sc = rsqrtf(red[0] / 96.f + 1e-6f);
  if (tid < 96) nq[row * 96 + tid] = acc * sc * qnw[tid];
}

// ---------------- 3. nkv + imp scores + gate partials + kr ----------------
__global__ __launch_bounds__(128) void nkv_kernel(const float* __restrict__ x,
                                                  const float* __restrict__ W_ckv,
                                                  const float* __restrict__ kvnw,
                                                  const float* __restrict__ W_imp,
                                                  const float* __restrict__ b_imp,
                                                  const float* __restrict__ W_gate,
                                                  const float* __restrict__ W_kr,
                                                  float* __restrict__ nkv,
                                                  float* __restrict__ scores,
                                                  float* __restrict__ gpart,
                                                  float* __restrict__ krtmp) {
  int row = blockIdx.x, tid = threadIdx.x;  // 128 thr
  __shared__ float xr[256];
  xr[tid] = x[row * 256 + tid];
  xr[tid + 128] = x[row * 256 + tid + 128];
  __syncthreads();
  const float* wp;
  int stride;
  if (tid < 32) { wp = W_ckv + tid; stride = 32; }
  else if (tid == 32) { wp = W_imp; stride = 1; }
  else if (tid < 36) { wp = W_gate + (tid - 33); stride = 3; }
  else if (tid < 100) { wp = W_kr + (tid - 36); stride = 64; }
  else { wp = W_ckv; stride = 0; }
  float acc = 0.f;
#pragma unroll 4
  for (int k = 0; k < 256; ++k) acc += xr[k] * wp[k * stride];
  float ss = acc * acc;
#pragma unroll
  for (int off = 16; off > 0; off >>= 1) ss += __shfl_xor(ss, off, 64);
  if (tid < 32) {
    float sc = rsqrtf(ss / 32.f + 1e-6f);
    nkv[row * 32 + tid] = acc * sc * kvnw[tid];
  } else if (tid == 32) {
    scores[row] = acc + b_imp[0];
  } else if (tid < 36) {
    gpart[row * 3 + (tid - 33)] = acc;
  } else if (tid < 100) {
    krtmp[row * 64 + (tid - 36)] = acc;
  }
}

// ---------------- generic 8-row projection GEMM ----------------
// out[row][col] = dot(A_row(row), W[:,col]); mode0: direct rows,
// mode1: sel-gathered x rows, mode2: attention-output gather.
__global__ __launch_bounds__(256) void proj8_kernel(const float* __restrict__ A,
                                                    const float* __restrict__ W,
                                                    float* __restrict__ Out,
                                                    const int* __restrict__ selidx,
                                                    int K, int NC, int Astride,
                                                    int OutStride, int outOff, int mode) {
  __shared__ __align__(16) float xT[4096];  // up to K=512 * 8 rows
  int row0 = blockIdx.x * 8;
  int tid = threadIdx.x;
  for (int i = tid; i < 8 * K; i += 256) {
    int r = i / K, k = i - r * K;
    int r0 = row0 + r;
    size_t addr;
    if (mode == 0) addr = (size_t)r0 * Astride + k;
    else if (mode == 1) {
      int b = r0 >> 9;
      addr = (size_t)(b * TT + selidx[r0]) * Astride + k;
    } else {
      int b = r0 >> 11, t = r0 & (TT - 1);
      addr = (size_t)((b * NHEAD + (k >> 5)) * TT + t) * 32 + (k & 31);
    }
    xT[k * 8 + r] = A[addr];
  }
  __syncthreads();
  for (int c = 0; c < NC; c += 256) {
    int col = c + tid;
    float acc0 = 0, acc1 = 0, acc2 = 0, acc3 = 0, acc4 = 0, acc5 = 0, acc6 = 0, acc7 = 0;
    const float* Wp = W + col;
#pragma unroll 4
    for (int k = 0; k < K; ++k) {
      float w = Wp[(size_t)k * NC];
      const float4 xa = *(const float4*)(xT + k * 8);
      const float4 xb = *(const float4*)(xT + k * 8 + 4);
      acc0 += w * xa.x; acc1 += w * xa.y; acc2 += w * xa.z; acc3 += w * xa.w;
      acc4 += w * xb.x; acc5 += w * xb.y; acc6 += w * xb.z; acc7 += w * xb.w;
    }
    float accs[8] = {acc0, acc1, acc2, acc3, acc4, acc5, acc6, acc7};
#pragma unroll
    for (int r = 0; r < 8; ++r)
      Out[(size_t)(row0 + r) * OutStride + outOff + col] = accs[r];
  }
}

// ---------------- rope in place on qtmp + krtmp ----------------
__global__ __launch_bounds__(256) void rope_kernel(const float* __restrict__ cos_t,
                                                   const float* __restrict__ sin_t,
                                                   float* __restrict__ qtmp,
                                                   float* __restrict__ krtmp) {
  int row = blockIdx.x, tid = threadIdx.x;
  int t = row & (TT - 1);
  for (int i = tid; i < 544; i += 256) {
    int dd = (i < 512) ? (i & 31) : (i - 512);
    float c = cos_t[t * 32 + dd], s = sin_t[t * 32 + dd];
    float* p0;
    if (i < 512) {
      int h = i >> 5;
      p0 = qtmp + (size_t)row * 1536 + 512 + h * 64 + dd;
    } else {
      p0 = krtmp + (size_t)row * 64 + dd;
    }
    float xr = p0[0], xi = p0[32];
    p0[0] = xr * c - xi * s;
    p0[32] = xr * s + xi * c;
  }
}

// ---------------- gate finalize ----------------
__global__ __launch_bounds__(256) void gate_kernel(const float* __restrict__ gpart,
                                                   const float* __restrict__ b_gate,
                                                   float* __restrict__ bw) {
  int tid = threadIdx.x;  // 256
  float a0 = 0, a1 = 0, a2 = 0, a3 = 0, a4 = 0, a5 = 0;
  for (int r = tid; r < 2 * TT; r += 256) {
    float g0 = gpart[r * 3], g1 = gpart[r * 3 + 1], g2 = gpart[r * 3 + 2];
    if (r < TT) { a0 += g0; a1 += g1; a2 += g2; }
    else { a3 += g0; a4 += g1; a5 += g2; }
  }
  __shared__ float red[6][256];
  red[0][tid] = a0; red[1][tid] = a1; red[2][tid] = a2;
  red[3][tid] = a3; red[4][tid] = a4; red[5][tid] = a5;
  __syncthreads();
  for (int s = 128; s > 0; s >>= 1) {
    if (tid < s) {
#pragma unroll
      for (int q = 0; q < 6; ++q) red[q][tid] += red[q][tid + s];
    }
    __syncthreads();
  }
  if (tid == 0) {
    for (int b = 0; b < 2; ++b) {
      float v[3];
      float mx = -INFINITY;
      for (int j = 0; j < 3; ++j) {
        v[j] = red[b * 3 + j][0] / (float)TT + b_gate[j];
        mx = fmaxf(mx, v[j]);
      }
      float sum = 0.f;
      for (int j = 0; j < 3; ++j) { v[j] = expf(v[j] - mx); sum += v[j]; }
      for (int j = 0; j < 3; ++j) bw[b * 3 + j] = v[j] / sum;
    }
  }
}

// ---------------- top-k (512 of 2048) via bitonic sort ----------------
__global__ __launch_bounds__(1024) void topk_kernel(const float* __restrict__ scores,
                                                    int* __restrict__ selidx) {
  int b = blockIdx.x, tid = threadIdx.x;  // 1024 thr
  __shared__ unsigned long long keys[TT];
  for (int i = tid; i < TT; i += 1024) {
    float s = scores[b * TT + i];
    unsigned u = __float_as_uint(s);
    u = (u & 0x80000000u) ? ~u : (u | 0x80000000u);  // ascending-sortable
    u = ~u;                                          // descending
    keys[i] = ((unsigned long long)u << 32) | (unsigned)i;
  }
  __syncthreads();
  for (int k = 2; k <= TT; k <<= 1) {
    for (int j = k >> 1; j > 0; j >>= 1) {
      for (int i = tid; i < TT; i += 1024) {
        int ixj = i ^ j;
        if (ixj > i) {
          unsigned long long a = keys[i], c = keys[ixj];
          bool sw = ((i & k) == 0) ? (a > c) : (a < c);
          if (sw) { keys[i] = c; keys[ixj] = a; }
        }
      }
      __syncthreads();
    }
  }
  if (tid < 512) selidx[b * 512 + tid] = (int)(keys[tid] & 0xffffffffu);
}

// ---------------- flash attention ----------------
// Q from qtmp (roped); K split: d<split from p1, else p2; V from pv.
// 64x64 tiles, 4x4 micro-tiles; LDS: Qt/Kt transposed stride 68; P aliases Kt.
__global__ __launch_bounds__(256) void flash_kernel(
    const float* __restrict__ qtmp,
    const float* __restrict__ p1, int rs1, int ho1, int split,
    const float* __restrict__ p2, int rs2, int ho2,
    const float* __restrict__ pv, int rsv, int hov,
    int Tk, int causal,
    const float* __restrict__ bw, int widx, int accum,
    float* __restrict__ attout) {
  __shared__ __align__(16) float Qt[96 * 68];
  __shared__ __align__(16) float KtPs[96 * 68];
  __shared__ __align__(16) float Vs[64 * 34];
  int qtile = blockIdx.x;
  int bh = blockIdx.y;
  int b = bh >> 4, h = bh & 15;
  int tid = threadIdx.x;
  int tq = tid >> 4, tk = tid & 15;
  const float scale = 0.1020620726159658f;  // 1/sqrt(96)

  int qrow0 = qtile * 64;
  for (int i = tid; i < 64 * 96; i += 256) {
    int qi = i / 96, d = i % 96;
    int trow = qrow0 + qi;
    int col = (d < 32) ? (h * 32 + d) : (512 + h * 64 + (d - 32));
    Qt[d * 68 + qi] = qtmp[(size_t)(b * TT + trow) * 1536 + col] * scale;
  }

  float m[4], l[4], o0[4], o1[4];
#pragma unroll
  for (int i = 0; i < 4; ++i) { m[i] = -INFINITY; l[i] = 0.f; o0[i] = 0.f; o1[i] = 0.f; }

  int nkt = causal ? (qtile + 1) : (Tk >> 6);
  for (int kt = 0; kt < nkt; ++kt) {
    __syncthreads();  // previous PV reads done
    int krow0 = kt * 64;
    for (int i = tid; i < 64 * 96; i += 256) {
      int kj = i / 96, d = i % 96;
      int trow = krow0 + kj;
      float val = (d < split)
                      ? p1[(size_t)(b * Tk + trow) * rs1 + h * ho1 + d]
                      : p2[(size_t)(b * Tk + trow) * rs2 + h * ho2 + (d - split)];
      KtPs[d * 68 + kj] = val;
    }
    for (int i = tid; i < 64 * 32; i += 256) {
      int kj = i >> 5, d = i & 31;
      Vs[kj * 34 + d] = pv[(size_t)(b * Tk + krow0 + kj) * rsv + h * hov + d];
    }
    __syncthreads();

    // S = Q K^T (scaled)
    float s[4][4];
#pragma unroll
    for (int i = 0; i < 4; ++i)
#pragma unroll
      for (int j = 0; j < 4; ++j) s[i][j] = 0.f;
#pragma unroll 4
    for (int d = 0; d < 96; ++d) {
      const float4 qv = *(const float4*)(Qt + d * 68 + 4 * tq);
      const float4 kv = *(const float4*)(KtPs + d * 68 + 4 * tk);
      float qa[4] = {qv.x, qv.y, qv.z, qv.w};
      float ka[4] = {kv.x, kv.y, kv.z, kv.w};
#pragma unroll
      for (int i = 0; i < 4; ++i)
#pragma unroll
        for (int j = 0; j < 4; ++j) s[i][j] += qa[i] * ka[j];
    }
    if (causal && kt == qtile) {
#pragma unroll
      for (int i = 0; i < 4; ++i) {
        int qg = qrow0 + 4 * tq + i;
#pragma unroll
        for (int j = 0; j < 4; ++j) {
          int kg = krow0 + 4 * tk + j;
          if (kg > qg) s[i][j] = -INFINITY;
        }
      }
    }
    // online softmax update (row groups of 16 lanes)
#pragma unroll
    for (int i = 0; i < 4; ++i) {
      float mx = fmaxf(fmaxf(s[i][0], s[i][1]), fmaxf(s[i][2], s[i][3]));
#pragma unroll
      for (int off = 8; off > 0; off >>= 1) mx = fmaxf(mx, __shfl_xor(mx, off, 64));
      float mn = fmaxf(m[i], mx);
      float alpha = __expf(m[i] - mn);
      float ps = 0.f;
#pragma unroll
      for (int j = 0; j < 4; ++j) { s[i][j] = __expf(s[i][j] - mn); ps += s[i][j]; }
#pragma unroll
      for (int off = 8; off > 0; off >>= 1) ps += __shfl_xor(ps, off, 64);
      l[i] = l[i] * alpha + ps;
      m[i] = mn;
      o0[i] *= alpha;
      o1[i] *= alpha;
    }
    __syncthreads();  // all K reads done; safe to overwrite with P
#pragma unroll
    for (int i = 0; i < 4; ++i)
      *(float4*)(KtPs + (4 * tq + i) * 68 + 4 * tk) =
          make_float4(s[i][0], s[i][1], s[i][2], s[i][3]);
    __syncthreads();
    // PV accumulate: this thread owns rows 4tq..+3, dims 2tk..2tk+1
#pragma unroll 2
    for (int kc = 0; kc < 16; ++kc) {
      float pr[4][4];
#pragma unroll
      for (int i = 0; i < 4; ++i) {
        float4 t4 = *(const float4*)(KtPs + (4 * tq + i) * 68 + 4 * kc);
        pr[i][0] = t4.x; pr[i][1] = t4.y; pr[i][2] = t4.z; pr[i][3] = t4.w;
      }
#pragma unroll
      for (int j = 0; j < 4; ++j) {
        float v0 = Vs[(4 * kc + j) * 34 + 2 * tk];
        float v1 = Vs[(4 * kc + j) * 34 + 2 * tk + 1];
#pragma unroll
        for (int i = 0; i < 4; ++i) {
          o0[i] += pr[i][j] * v0;
          o1[i] += pr[i][j] * v1;
        }
      }
    }
  }

  float w = bw[b * 3 + widx];
#pragma unroll
  for (int i = 0; i < 4; ++i) {
    float inv = w / l[i];
    int trow = qrow0 + 4 * tq + i;
    size_t idx = (size_t)(bh * TT + trow) * 32 + 2 * tk;
    float r0 = o0[i] * inv, r1 = o1[i] * inv;
    if (accum) {
      attout[idx] += r0;
      attout[idx + 1] += r1;
    } else {
      attout[idx] = r0;
      attout[idx + 1] = r1;
    }
  }
}

// ---------------- launch ----------------
extern "C" void kernel_launch(void* const* d_in, const int* in_sizes, int n_in,
                              void* d_out, int out_size, void* d_ws, size_t ws_size,
                              hipStream_t stream) {
  const float* x      = (const float*)d_in[0];
  const float* W_cq   = (const float*)d_in[1];
  const float* qnw    = (const float*)d_in[2];
  const float* W_dqn  = (const float*)d_in[3];
  const float* W_dqr  = (const float*)d_in[4];
  const float* W_ckv  = (const float*)d_in[5];
  const float* kvnw   = (const float*)d_in[6];
  const float* W_dkn  = (const float*)d_in[7];
  const float* W_dv   = (const float*)d_in[8];
  const float* W_kr   = (const float*)d_in[9];
  const float* W_imp  = (const float*)d_in[10];
  const float* b_imp  = (const float*)d_in[11];
  const float* W_selk = (const float*)d_in[12];
  const float* W_selv = (const float*)d_in[13];
  const float* W_wink = (const float*)d_in[14];
  const float* W_winv = (const float*)d_in[15];
  const float* W_gate = (const float*)d_in[16];
  const float* b_gate = (const float*)d_in[17];
  const float* W_proj = (const float*)d_in[18];
  const float* cos_f  = (const float*)d_in[19];
  const float* sin_f  = (const float*)d_in[20];
  float* out = (float*)d_out;
  float* ws  = (float*)d_ws;

  size_t off = 0;
  auto alloc = [&](size_t n) {
    float* p = ws + off;
    off += (n + 255) & ~(size_t)255;
    return p;
  };
  const int ROWS = 2 * TT;  // 4096
  float* xh     = alloc((size_t)ROWS * 256);
  float* nq     = alloc((size_t)ROWS * 96);
  float* qtmp   = alloc((size_t)ROWS * 1536);
  float* nkv    = alloc((size_t)ROWS * 32);
  float* kvtmp  = alloc((size_t)ROWS * 1024);
  float* krtmp  = alloc((size_t)ROWS * 64);
  float* scores = alloc(ROWS);
  float* gpart  = alloc((size_t)ROWS * 3);
  float* bwp    = alloc(8);
  int* selidx   = (int*)alloc(1024);
  float* seltmp = alloc((size_t)1024 * 2048);
  float* wintmp = alloc((size_t)ROWS * 2048);
  float* attout = alloc((size_t)32 * TT * 32);

  logmap_kernel<<<ROWS, 256, 0, stream>>>(x, xh);
  nq_kernel<<<ROWS, 128, 0, stream>>>(xh, W_cq, qnw, nq);
  // qtmp = [nq@W_dqn (512) | nq@W_dqr (1024)]
  proj8_kernel<<<ROWS / 8, 256, 0, stream>>>(nq, W_dqn, qtmp, nullptr, 96, 512, 96, 1536, 0, 0);
  proj8_kernel<<<ROWS / 8, 256, 0, stream>>>(nq, W_dqr, qtmp, nullptr, 96, 1024, 96, 1536, 512, 0);
  nkv_kernel<<<ROWS, 128, 0, stream>>>(x, W_ckv, kvnw, W_imp, b_imp, W_gate, W_kr,
                                       nkv, scores, gpart, krtmp);
  // kvtmp = [kn (512) | v (512)]
  proj8_kernel<<<ROWS / 8, 256, 0, stream>>>(nkv, W_dkn, kvtmp, nullptr, 32, 512, 32, 1024, 0, 0);
  proj8_kernel<<<ROWS / 8, 256, 0, stream>>>(nkv, W_dv, kvtmp, nullptr, 32, 512, 32, 1024, 512, 0);
  rope_kernel<<<ROWS, 256, 0, stream>>>(cos_f, sin_f, qtmp, krtmp);
  gate_kernel<<<1, 256, 0, stream>>>(gpart, b_gate, bwp);
  topk_kernel<<<2, 1024, 0, stream>>>(scores, selidx);
  // seltmp = [sk (1536) | sv (512)] on gathered rows
  proj8_kernel<<<128, 256, 0, stream>>>(x, W_selk, seltmp, selidx, 256, 1536, 256, 2048, 0, 1);
  proj8_kernel<<<128, 256, 0, stream>>>(x, W_selv, seltmp, selidx, 256, 512, 256, 2048, 1536, 1);
  // wintmp = [wk (1536) | wv (512)]
  proj8_kernel<<<ROWS / 8, 256, 0, stream>>>(x, W_wink, wintmp, nullptr, 256, 1536, 256, 2048, 0, 0);
  proj8_kernel<<<ROWS / 8, 256, 0, stream>>>(x, W_winv, wintmp, nullptr, 256, 512, 256, 2048, 1536, 0);

  dim3 fg(TT / 64, 32);
  // cmp: K = [kn | kr(broadcast)], V from kvtmp+512
  flash_kernel<<<fg, 256, 0, stream>>>(qtmp, kvtmp, 1024, 32, 32, krtmp, 64, 0,
                                       kvtmp + 512, 1024, 32, TT, 1, bwp, 0, 0, attout);
  // sel: K/V from seltmp, 512 keys, non-causal
  flash_kernel<<<fg, 256, 0, stream>>>(qtmp, seltmp, 2048, 96, 96, nullptr, 0, 0,
                                       seltmp + 1536, 2048, 32, 512, 0, bwp, 1, 1, attout);
  // win: K/V from wintmp, causal
  flash_kernel<<<fg, 256, 0, stream>>>(qtmp, wintmp, 2048, 96, 96, nullptr, 0, 0,
                                       wintmp + 1536, 2048, 32, TT, 1, bwp, 2, 1, attout);

  // final projection: (B,T,512) @ W_proj -> out
  proj8_kernel<<<ROWS / 8, 256, 0, stream>>>(attout, W_proj, out, nullptr, 512, 256, 0, 256, 0, 2);
}

// Round 2
// 1286.536 us; speedup vs baseline: 2.3178x; 2.3178x over previous
//
#include <hip/hip_runtime.h>
#include <hip/hip_bf16.h>
#include <math.h>

#define TT 2048
#define NE 256
#define NHEAD 16

typedef __attribute__((ext_vector_type(8))) short bf16x8;
typedef __attribute__((ext_vector_type(4))) float f32x4;

__device__ __forceinline__ short f2bf(float x) {
  __hip_bfloat16 h = __float2bfloat16(x);
  return *reinterpret_cast<short*>(&h);
}
__device__ __forceinline__ unsigned pack2bf(float a, float b) {
  return (unsigned)(unsigned short)f2bf(a) | ((unsigned)(unsigned short)f2bf(b) << 16);
}

// ---------------- block reduce (256 threads) ----------------
__device__ __forceinline__ float blk_sum(float v, float* red, int tid) {
#pragma unroll
  for (int off = 32; off > 0; off >>= 1) v += __shfl_down(v, off, 64);
  __syncthreads();
  if ((tid & 63) == 0) red[tid >> 6] = v;
  __syncthreads();
  return red[0] + red[1] + red[2] + red[3];
}

// ---------------- 1. logmap ----------------
__global__ __launch_bounds__(256) void logmap_kernel(const float* __restrict__ x,
                                                     float* __restrict__ xh) {
  __shared__ float red[4];
  int row = blockIdx.x, tid = threadIdx.x;
  int t = row & (TT - 1);
  float uv = x[row * NE + tid];
  float rv = (t == 0) ? 0.f : x[row * NE - NE + tid];
  float xn2 = blk_sum(rv * rv, red, tid);
  float un2 = blk_sum(uv * uv, red, tid);
  float ip  = blk_sum(-rv * uv, red, tid);
  float den = 1.f + 2.f * ip + xn2 * un2;
  float mob = ((1.f + 2.f * ip + un2) * (-rv) + (1.f - xn2) * uv) / den;
  float an2 = blk_sum(mob * mob, red, tid);
  float an = sqrtf(an2);
  float cf = 1.f + xn2;
  float arg = fminf(sqrtf(an), 0.999f);
  xh[row * NE + tid] = cf * atanhf(arg) * mob / an;
}

// ---------------- 2. nq = rmsnorm(xh @ W_cq) ----------------
__global__ __launch_bounds__(128) void nq_kernel(const float* __restrict__ xh,
                                                 const float* __restrict__ W_cq,
                                                 const float* __restrict__ qnw,
                                                 float* __restrict__ nq) {
  int row = blockIdx.x, tid = threadIdx.x;  // 128 thr
  __shared__ float xr[256];
  __shared__ float red[128];
  xr[tid] = xh[row * 256 + tid];
  xr[tid + 128] = xh[row * 256 + tid + 128];
  __syncthreads();
  float acc = 0.f;
  if (tid < 96) {
    const float* wp = W_cq + tid;
#pragma unroll 4
    for (int k = 0; k < 256; ++k) acc += xr[k] * wp[k * 96];
  }
  red[tid] = (tid < 96) ? acc * acc : 0.f;
  __syncthreads();
  for (int s = 64; s > 0; s >>= 1) {
    if (tid < s) red[tid] += red[tid + s];
    __syncthreads();
  }
  float sc = rsqrtf(red[0] / 96.f + 1e-6f);
  if (tid < 96) nq[row * 96 + tid] = acc * sc * qnw[tid];
}

// ---------------- 3. nkv + imp scores + gate partials + kr ----------------
__global__ __launch_bounds__(128) void nkv_kernel(const float* __restrict__ x,
                                                  const float* __restrict__ W_ckv,
                                                  const float* __restrict__ kvnw,
                                                  const float* __restrict__ W_imp,
                                                  const float* __restrict__ b_imp,
                                                  const float* __restrict__ W_gate,
                                                  const float* __restrict__ W_kr,
                                                  float* __restrict__ nkv,
                                                  float* __restrict__ scores,
                                                  float* __restrict__ gpart,
                                                  float* __restrict__ krtmp) {
  int row = blockIdx.x, tid = threadIdx.x;  // 128 thr
  __shared__ float xr[256];
  xr[tid] = x[row * 256 + tid];
  xr[tid + 128] = x[row * 256 + tid + 128];
  __syncthreads();
  const float* wp;
  int stride;
  if (tid < 32) { wp = W_ckv + tid; stride = 32; }
  else if (tid == 32) { wp = W_imp; stride = 1; }
  else if (tid < 36) { wp = W_gate + (tid - 33); stride = 3; }
  else if (tid < 100) { wp = W_kr + (tid - 36); stride = 64; }
  else { wp = W_ckv; stride = 0; }
  float acc = 0.f;
#pragma unroll 4
  for (int k = 0; k < 256; ++k) acc += xr[k] * wp[k * stride];
  float ss = acc * acc;
#pragma unroll
  for (int off = 16; off > 0; off >>= 1) ss += __shfl_xor(ss, off, 64);
  if (tid < 32) {
    float sc = rsqrtf(ss / 32.f + 1e-6f);
    nkv[row * 32 + tid] = acc * sc * kvnw[tid];
  } else if (tid == 32) {
    scores[row] = acc + b_imp[0];
  } else if (tid < 36) {
    gpart[row * 3 + (tid - 33)] = acc;
  } else if (tid < 100) {
    krtmp[row * 64 + (tid - 36)] = acc;
  }
}

// ---------------- generic 8-row projection GEMM ----------------
__global__ __launch_bounds__(256) void proj8_kernel(const float* __restrict__ A,
                                                    const float* __restrict__ W,
                                                    float* __restrict__ Out,
                                                    const int* __restrict__ selidx,
                                                    int K, int NC, int Astride,
                                                    int OutStride, int outOff, int mode) {
  __shared__ __align__(16) float xT[4096];  // up to K=512 * 8 rows
  int row0 = blockIdx.x * 8;
  int tid = threadIdx.x;
  for (int i = tid; i < 8 * K; i += 256) {
    int r = i / K, k = i - r * K;
    int r0 = row0 + r;
    size_t addr;
    if (mode == 0) addr = (size_t)r0 * Astride + k;
    else if (mode == 1) {
      int b = r0 >> 9;
      addr = (size_t)(b * TT + selidx[r0]) * Astride + k;
    } else {
      int b = r0 >> 11, t = r0 & (TT - 1);
      addr = (size_t)((b * NHEAD + (k >> 5)) * TT + t) * 32 + (k & 31);
    }
    xT[k * 8 + r] = A[addr];
  }
  __syncthreads();
  for (int c = 0; c < NC; c += 256) {
    int col = c + tid;
    float acc0 = 0, acc1 = 0, acc2 = 0, acc3 = 0, acc4 = 0, acc5 = 0, acc6 = 0, acc7 = 0;
    const float* Wp = W + col;
#pragma unroll 4
    for (int k = 0; k < K; ++k) {
      float w = Wp[(size_t)k * NC];
      const float4 xa = *(const float4*)(xT + k * 8);
      const float4 xb = *(const float4*)(xT + k * 8 + 4);
      acc0 += w * xa.x; acc1 += w * xa.y; acc2 += w * xa.z; acc3 += w * xa.w;
      acc4 += w * xb.x; acc5 += w * xb.y; acc6 += w * xb.z; acc7 += w * xb.w;
    }
    float accs[8] = {acc0, acc1, acc2, acc3, acc4, acc5, acc6, acc7};
#pragma unroll
    for (int r = 0; r < 8; ++r)
      Out[(size_t)(row0 + r) * OutStride + outOff + col] = accs[r];
  }
}

// ---------------- rope in place on qtmp + krtmp ----------------
__global__ __launch_bounds__(256) void rope_kernel(const float* __restrict__ cos_t,
                                                   const float* __restrict__ sin_t,
                                                   float* __restrict__ qtmp,
                                                   float* __restrict__ krtmp) {
  int row = blockIdx.x, tid = threadIdx.x;
  int t = row & (TT - 1);
  for (int i = tid; i < 544; i += 256) {
    int dd = (i < 512) ? (i & 31) : (i - 512);
    float c = cos_t[t * 32 + dd], s = sin_t[t * 32 + dd];
    float* p0;
    if (i < 512) {
      int h = i >> 5;
      p0 = qtmp + (size_t)row * 1536 + 512 + h * 64 + dd;
    } else {
      p0 = krtmp + (size_t)row * 64 + dd;
    }
    float xr = p0[0], xi = p0[32];
    p0[0] = xr * c - xi * s;
    p0[32] = xr * s + xi * c;
  }
}

// ---------------- gate finalize ----------------
__global__ __launch_bounds__(256) void gate_kernel(const float* __restrict__ gpart,
                                                   const float* __restrict__ b_gate,
                                                   float* __restrict__ bw) {
  int tid = threadIdx.x;  // 256
  float a0 = 0, a1 = 0, a2 = 0, a3 = 0, a4 = 0, a5 = 0;
  for (int r = tid; r < 2 * TT; r += 256) {
    float g0 = gpart[r * 3], g1 = gpart[r * 3 + 1], g2 = gpart[r * 3 + 2];
    if (r < TT) { a0 += g0; a1 += g1; a2 += g2; }
    else { a3 += g0; a4 += g1; a5 += g2; }
  }
  __shared__ float red[6][256];
  red[0][tid] = a0; red[1][tid] = a1; red[2][tid] = a2;
  red[3][tid] = a3; red[4][tid] = a4; red[5][tid] = a5;
  __syncthreads();
  for (int s = 128; s > 0; s >>= 1) {
    if (tid < s) {
#pragma unroll
      for (int q = 0; q < 6; ++q) red[q][tid] += red[q][tid + s];
    }
    __syncthreads();
  }
  if (tid == 0) {
    for (int b = 0; b < 2; ++b) {
      float v[3];
      float mx = -INFINITY;
      for (int j = 0; j < 3; ++j) {
        v[j] = red[b * 3 + j][0] / (float)TT + b_gate[j];
        mx = fmaxf(mx, v[j]);
      }
      float sum = 0.f;
      for (int j = 0; j < 3; ++j) { v[j] = expf(v[j] - mx); sum += v[j]; }
      for (int j = 0; j < 3; ++j) bw[b * 3 + j] = v[j] / sum;
    }
  }
}

// ---------------- top-k (512 of 2048) via bitonic sort ----------------
__global__ __launch_bounds__(1024) void topk_kernel(const float* __restrict__ scores,
                                                    int* __restrict__ selidx) {
  int b = blockIdx.x, tid = threadIdx.x;  // 1024 thr
  __shared__ unsigned long long keys[TT];
  for (int i = tid; i < TT; i += 1024) {
    float s = scores[b * TT + i];
    unsigned u = __float_as_uint(s);
    u = (u & 0x80000000u) ? ~u : (u | 0x80000000u);  // ascending-sortable
    u = ~u;                                          // descending
    keys[i] = ((unsigned long long)u << 32) | (unsigned)i;
  }
  __syncthreads();
  for (int k = 2; k <= TT; k <<= 1) {
    for (int j = k >> 1; j > 0; j >>= 1) {
      for (int i = tid; i < TT; i += 1024) {
        int ixj = i ^ j;
        if (ixj > i) {
          unsigned long long a = keys[i], c = keys[ixj];
          bool sw = ((i & k) == 0) ? (a > c) : (a < c);
          if (sw) { keys[i] = c; keys[ixj] = a; }
        }
      }
      __syncthreads();
    }
  }
  if (tid < 512) selidx[b * 512 + tid] = (int)(keys[tid] & 0xffffffffu);
}

// ---------------- MFMA flash attention ----------------
// 64 Q-rows x 64 K-cols per block, 4 waves, wave wv owns q-rows 16*wv..16*wv+15.
// bf16 MFMA 16x16x32; P round-trips through wave-private LDS (C-layout -> A-layout).
// LDS strides: Q/K 104 shorts (2-way only on b128 reads), Vt/Ps 72 shorts.
__global__ __launch_bounds__(256) void flash_kernel(
    const float* __restrict__ qtmp,
    const float* __restrict__ p1, int rs1, int ho1, int split,
    const float* __restrict__ p2, int rs2, int ho2,
    const float* __restrict__ pv, int rsv, int hov,
    int Tk, int causal,
    const float* __restrict__ bw, int widx, int accum,
    float* __restrict__ attout) {
  __shared__ __align__(16) short Qs[64 * 104];
  __shared__ __align__(16) short Ks[64 * 104];
  __shared__ __align__(16) short Vts[32 * 72];
  __shared__ __align__(16) short Ps[4 * 16 * 72];

  int qtile = blockIdx.x;
  int bh = blockIdx.y;
  int b = bh >> 4, h = bh & 15;
  int tid = threadIdx.x;
  int wv = tid >> 6, lane = tid & 63;
  int l15 = lane & 15, quad = lane >> 4;
  const float scale = 0.1020620726159658f;  // 1/sqrt(96)

  int qrow0 = qtile * 64;
  // ---- stage Q (64 x 96) -> bf16, scale folded, packed b32 writes ----
  for (int i = tid; i < 64 * 48; i += 256) {
    int qi = i / 48, dp = (i - qi * 48) * 2;
    int col = (dp < 32) ? (h * 32 + dp) : (512 + h * 64 + (dp - 32));
    const float2 q2 = *(const float2*)(qtmp + (size_t)(b * TT + qrow0 + qi) * 1536 + col);
    *(unsigned*)(Qs + qi * 104 + dp) = pack2bf(q2.x * scale, q2.y * scale);
  }

  float m[4], l[4], alpha[4];
  f32x4 of[2];
#pragma unroll
  for (int i = 0; i < 4; ++i) { m[i] = -INFINITY; l[i] = 0.f; }
  of[0] = (f32x4){0.f, 0.f, 0.f, 0.f};
  of[1] = (f32x4){0.f, 0.f, 0.f, 0.f};

  int nkt = causal ? (qtile + 1) : (Tk >> 6);
  for (int kt = 0; kt < nkt; ++kt) {
    __syncthreads();  // previous tile's LDS reads complete
    int krow0 = kt * 64;
    // ---- stage K (64 x 96) ----
    for (int i = tid; i < 64 * 48; i += 256) {
      int kj = i / 48, dp = (i - kj * 48) * 2;
      int trow = krow0 + kj;
      const float* src = (dp < split)
                             ? (p1 + (size_t)(b * Tk + trow) * rs1 + h * ho1 + dp)
                             : (p2 + (size_t)(b * Tk + trow) * rs2 + h * ho2 + (dp - split));
      const float2 k2 = *(const float2*)src;
      *(unsigned*)(Ks + kj * 104 + dp) = pack2bf(k2.x, k2.y);
    }
    // ---- stage V transposed (32 x 64) ----
    for (int i = tid; i < 2048; i += 256) {
      int kj = i >> 5, d = i & 31;
      Vts[d * 72 + kj] = f2bf(pv[(size_t)(b * Tk + krow0 + kj) * rsv + h * hov + d]);
    }
    __syncthreads();

    // ---- S = Q K^T via MFMA: wave computes 16 x 64 ----
    f32x4 sf[4];
#pragma unroll
    for (int nb = 0; nb < 4; ++nb) sf[nb] = (f32x4){0.f, 0.f, 0.f, 0.f};
#pragma unroll
    for (int ks = 0; ks < 3; ++ks) {
      bf16x8 aq = *(const bf16x8*)(Qs + (wv * 16 + l15) * 104 + ks * 32 + quad * 8);
#pragma unroll
      for (int nb = 0; nb < 4; ++nb) {
        bf16x8 bk = *(const bf16x8*)(Ks + (nb * 16 + l15) * 104 + ks * 32 + quad * 8);
        sf[nb] = __builtin_amdgcn_mfma_f32_16x16x32_bf16(aq, bk, sf[nb], 0, 0, 0);
      }
    }
    // C-layout: sf[nb][reg] = S[quad*4+reg][nb*16+l15]
    if (causal && kt == qtile) {
      int rowg = qrow0 + wv * 16 + quad * 4;
#pragma unroll
      for (int reg = 0; reg < 4; ++reg) {
#pragma unroll
        for (int nb = 0; nb < 4; ++nb) {
          int colg = krow0 + nb * 16 + l15;
          if (colg > rowg + reg) sf[nb][reg] = -INFINITY;
        }
      }
    }
    // ---- online softmax (rows owned by 16-lane groups sharing quad) ----
    short* Pw = Ps + wv * 16 * 72;
#pragma unroll
    for (int reg = 0; reg < 4; ++reg) {
      float mx = fmaxf(fmaxf(sf[0][reg], sf[1][reg]), fmaxf(sf[2][reg], sf[3][reg]));
#pragma unroll
      for (int off = 8; off > 0; off >>= 1) mx = fmaxf(mx, __shfl_xor(mx, off, 64));
      float mn = fmaxf(m[reg], mx);
      alpha[reg] = __expf(m[reg] - mn);
      m[reg] = mn;
      float ps = 0.f;
#pragma unroll
      for (int nb = 0; nb < 4; ++nb) {
        float p = __expf(sf[nb][reg] - mn);
        ps += p;
        Pw[(quad * 4 + reg) * 72 + nb * 16 + l15] = f2bf(p);
      }
#pragma unroll
      for (int off = 8; off > 0; off >>= 1) ps += __shfl_xor(ps, off, 64);
      l[reg] = l[reg] * alpha[reg] + ps;
      of[0][reg] *= alpha[reg];
      of[1][reg] *= alpha[reg];
    }
    // wave-private P: only need in-wave LDS ordering, no barrier
    asm volatile("s_waitcnt lgkmcnt(0)" ::: "memory");

    // ---- O += P V via MFMA (16 x 32) ----
#pragma unroll
    for (int ks2 = 0; ks2 < 2; ++ks2) {
      bf16x8 ap = *(const bf16x8*)(Pw + l15 * 72 + ks2 * 32 + quad * 8);
#pragma unroll
      for (int vn = 0; vn < 2; ++vn) {
        bf16x8 bv = *(const bf16x8*)(Vts + (vn * 16 + l15) * 72 + ks2 * 32 + quad * 8);
        of[vn] = __builtin_amdgcn_mfma_f32_16x16x32_bf16(ap, bv, of[vn], 0, 0, 0);
      }
    }
  }

  // ---- epilogue ----
  float wgt = bw[b * 3 + widx];
#pragma unroll
  for (int reg = 0; reg < 4; ++reg) {
    float inv = wgt / l[reg];
    int trow = qrow0 + wv * 16 + quad * 4 + reg;
#pragma unroll
    for (int vn = 0; vn < 2; ++vn) {
      size_t idx = (size_t)(bh * TT + trow) * 32 + vn * 16 + l15;
      float r = of[vn][reg] * inv;
      if (accum) attout[idx] += r;
      else attout[idx] = r;
    }
  }
}

// ---------------- launch ----------------
extern "C" void kernel_launch(void* const* d_in, const int* in_sizes, int n_in,
                              void* d_out, int out_size, void* d_ws, size_t ws_size,
                              hipStream_t stream) {
  const float* x      = (const float*)d_in[0];
  const float* W_cq   = (const float*)d_in[1];
  const float* qnw    = (const float*)d_in[2];
  const float* W_dqn  = (const float*)d_in[3];
  const float* W_dqr  = (const float*)d_in[4];
  const float* W_ckv  = (const float*)d_in[5];
  const float* kvnw   = (const float*)d_in[6];
  const float* W_dkn  = (const float*)d_in[7];
  const float* W_dv   = (const float*)d_in[8];
  const float* W_kr   = (const float*)d_in[9];
  const float* W_imp  = (const float*)d_in[10];
  const float* b_imp  = (const float*)d_in[11];
  const float* W_selk = (const float*)d_in[12];
  const float* W_selv = (const float*)d_in[13];
  const float* W_wink = (const float*)d_in[14];
  const float* W_winv = (const float*)d_in[15];
  const float* W_gate = (const float*)d_in[16];
  const float* b_gate = (const float*)d_in[17];
  const float* W_proj = (const float*)d_in[18];
  const float* cos_f  = (const float*)d_in[19];
  const float* sin_f  = (const float*)d_in[20];
  float* out = (float*)d_out;
  float* ws  = (float*)d_ws;

  size_t off = 0;
  auto alloc = [&](size_t n) {
    float* p = ws + off;
    off += (n + 255) & ~(size_t)255;
    return p;
  };
  const int ROWS = 2 * TT;  // 4096
  float* xh     = alloc((size_t)ROWS * 256);
  float* nq     = alloc((size_t)ROWS * 96);
  float* qtmp   = alloc((size_t)ROWS * 1536);
  float* nkv    = alloc((size_t)ROWS * 32);
  float* kvtmp  = alloc((size_t)ROWS * 1024);
  float* krtmp  = alloc((size_t)ROWS * 64);
  float* scores = alloc(ROWS);
  float* gpart  = alloc((size_t)ROWS * 3);
  float* bwp    = alloc(8);
  int* selidx   = (int*)alloc(1024);
  float* seltmp = alloc((size_t)1024 * 2048);
  float* wintmp = alloc((size_t)ROWS * 2048);
  float* attout = alloc((size_t)32 * TT * 32);

  logmap_kernel<<<ROWS, 256, 0, stream>>>(x, xh);
  nq_kernel<<<ROWS, 128, 0, stream>>>(xh, W_cq, qnw, nq);
  proj8_kernel<<<ROWS / 8, 256, 0, stream>>>(nq, W_dqn, qtmp, nullptr, 96, 512, 96, 1536, 0, 0);
  proj8_kernel<<<ROWS / 8, 256, 0, stream>>>(nq, W_dqr, qtmp, nullptr, 96, 1024, 96, 1536, 512, 0);
  nkv_kernel<<<ROWS, 128, 0, stream>>>(x, W_ckv, kvnw, W_imp, b_imp, W_gate, W_kr,
                                       nkv, scores, gpart, krtmp);
  proj8_kernel<<<ROWS / 8, 256, 0, stream>>>(nkv, W_dkn, kvtmp, nullptr, 32, 512, 32, 1024, 0, 0);
  proj8_kernel<<<ROWS / 8, 256, 0, stream>>>(nkv, W_dv, kvtmp, nullptr, 32, 512, 32, 1024, 512, 0);
  rope_kernel<<<ROWS, 256, 0, stream>>>(cos_f, sin_f, qtmp, krtmp);
  gate_kernel<<<1, 256, 0, stream>>>(gpart, b_gate, bwp);
  topk_kernel<<<2, 1024, 0, stream>>>(scores, selidx);
  proj8_kernel<<<128, 256, 0, stream>>>(x, W_selk, seltmp, selidx, 256, 1536, 256, 2048, 0, 1);
  proj8_kernel<<<128, 256, 0, stream>>>(x, W_selv, seltmp, selidx, 256, 512, 256, 2048, 1536, 1);
  proj8_kernel<<<ROWS / 8, 256, 0, stream>>>(x, W_wink, wintmp, nullptr, 256, 1536, 256, 2048, 0, 0);
  proj8_kernel<<<ROWS / 8, 256, 0, stream>>>(x, W_winv, wintmp, nullptr, 256, 512, 256, 2048, 1536, 0);

  dim3 fg(TT / 64, 32);
  // cmp: K = [kn | kr(broadcast via ho2=0)], V = kvtmp+512
  flash_kernel<<<fg, 256, 0, stream>>>(qtmp, kvtmp, 1024, 32, 32, krtmp, 64, 0,
                                       kvtmp + 512, 1024, 32, TT, 1, bwp, 0, 0, attout);
  // sel: 512 keys, non-causal
  flash_kernel<<<fg, 256, 0, stream>>>(qtmp, seltmp, 2048, 96, 96, seltmp, 2048, 96,
                                       seltmp + 1536, 2048, 32, 512, 0, bwp, 1, 1, attout);
  // win: causal
  flash_kernel<<<fg, 256, 0, stream>>>(qtmp, wintmp, 2048, 96, 96, wintmp, 2048, 96,
                                       wintmp + 1536, 2048, 32, TT, 1, bwp, 2, 1, attout);

  proj8_kernel<<<ROWS / 8, 256, 0, stream>>>(attout, W_proj, out, nullptr, 512, 256, 0, 256, 0, 2);
}

// Round 3
// 988.041 us; speedup vs baseline: 3.0180x; 1.3021x over previous
//
#include <hip/hip_runtime.h>
#include <hip/hip_bf16.h>
#include <math.h>

#define TT 2048
#define NE 256
#define NHEAD 16

typedef __attribute__((ext_vector_type(8))) short bf16x8;
typedef __attribute__((ext_vector_type(4))) float f32x4;
typedef unsigned short ushort;

__device__ __forceinline__ short f2bf(float x) {
  __hip_bfloat16 h = __float2bfloat16(x);
  return *reinterpret_cast<short*>(&h);
}
__device__ __forceinline__ unsigned pack2bf(float a, float b) {
  return (unsigned)(ushort)f2bf(a) | ((unsigned)(ushort)f2bf(b) << 16);
}

// ---------------- block reduce (256 threads) ----------------
__device__ __forceinline__ float blk_sum(float v, float* red, int tid) {
#pragma unroll
  for (int off = 32; off > 0; off >>= 1) v += __shfl_down(v, off, 64);
  __syncthreads();
  if ((tid & 63) == 0) red[tid >> 6] = v;
  __syncthreads();
  return red[0] + red[1] + red[2] + red[3];
}

// ---------------- 1. logmap ----------------
__global__ __launch_bounds__(256) void logmap_kernel(const float* __restrict__ x,
                                                     float* __restrict__ xh) {
  __shared__ float red[4];
  int row = blockIdx.x, tid = threadIdx.x;
  int t = row & (TT - 1);
  float uv = x[row * NE + tid];
  float rv = (t == 0) ? 0.f : x[row * NE - NE + tid];
  float xn2 = blk_sum(rv * rv, red, tid);
  float un2 = blk_sum(uv * uv, red, tid);
  float ip  = blk_sum(-rv * uv, red, tid);
  float den = 1.f + 2.f * ip + xn2 * un2;
  float mob = ((1.f + 2.f * ip + un2) * (-rv) + (1.f - xn2) * uv) / den;
  float an2 = blk_sum(mob * mob, red, tid);
  float an = sqrtf(an2);
  float cf = 1.f + xn2;
  float arg = fminf(sqrtf(an), 0.999f);
  xh[row * NE + tid] = cf * atanhf(arg) * mob / an;
}

// ---------------- 2. nq = rmsnorm(xh @ W_cq) ----------------
__global__ __launch_bounds__(128) void nq_kernel(const float* __restrict__ xh,
                                                 const float* __restrict__ W_cq,
                                                 const float* __restrict__ qnw,
                                                 float* __restrict__ nq) {
  int row = blockIdx.x, tid = threadIdx.x;  // 128 thr
  __shared__ float xr[256];
  __shared__ float red[128];
  xr[tid] = xh[row * 256 + tid];
  xr[tid + 128] = xh[row * 256 + tid + 128];
  __syncthreads();
  float acc = 0.f;
  if (tid < 96) {
    const float* wp = W_cq + tid;
#pragma unroll 4
    for (int k = 0; k < 256; ++k) acc += xr[k] * wp[k * 96];
  }
  red[tid] = (tid < 96) ? acc * acc : 0.f;
  __syncthreads();
  for (int s = 64; s > 0; s >>= 1) {
    if (tid < s) red[tid] += red[tid + s];
    __syncthreads();
  }
  float sc = rsqrtf(red[0] / 96.f + 1e-6f);
  if (tid < 96) nq[row * 96 + tid] = acc * sc * qnw[tid];
}

// ---------------- 3. nkv + imp scores + gate partials + kr ----------------
__global__ __launch_bounds__(128) void nkv_kernel(const float* __restrict__ x,
                                                  const float* __restrict__ W_ckv,
                                                  const float* __restrict__ kvnw,
                                                  const float* __restrict__ W_imp,
                                                  const float* __restrict__ b_imp,
                                                  const float* __restrict__ W_gate,
                                                  const float* __restrict__ W_kr,
                                                  float* __restrict__ nkv,
                                                  float* __restrict__ scores,
                                                  float* __restrict__ gpart,
                                                  float* __restrict__ krtmp) {
  int row = blockIdx.x, tid = threadIdx.x;  // 128 thr
  __shared__ float xr[256];
  xr[tid] = x[row * 256 + tid];
  xr[tid + 128] = x[row * 256 + tid + 128];
  __syncthreads();
  const float* wp;
  int stride;
  if (tid < 32) { wp = W_ckv + tid; stride = 32; }
  else if (tid == 32) { wp = W_imp; stride = 1; }
  else if (tid < 36) { wp = W_gate + (tid - 33); stride = 3; }
  else if (tid < 100) { wp = W_kr + (tid - 36); stride = 64; }
  else { wp = W_ckv; stride = 0; }
  float acc = 0.f;
#pragma unroll 4
  for (int k = 0; k < 256; ++k) acc += xr[k] * wp[k * stride];
  float ss = acc * acc;
#pragma unroll
  for (int off = 16; off > 0; off >>= 1) ss += __shfl_xor(ss, off, 64);
  if (tid < 32) {
    float sc = rsqrtf(ss / 32.f + 1e-6f);
    nkv[row * 32 + tid] = acc * sc * kvnw[tid];
  } else if (tid == 32) {
    scores[row] = acc + b_imp[0];
  } else if (tid < 36) {
    gpart[row * 3 + (tid - 33)] = acc;
  } else if (tid < 100) {
    krtmp[row * 64 + (tid - 36)] = acc;
  }
}

// ---------------- generic 8-row projection GEMM ----------------
__global__ __launch_bounds__(256) void proj8_kernel(const float* __restrict__ A,
                                                    const float* __restrict__ W,
                                                    void* __restrict__ Out,
                                                    const int* __restrict__ selidx,
                                                    int K, int NC, int Astride,
                                                    int OutStride, int outOff, int mode,
                                                    int obf16) {
  __shared__ __align__(16) float xT[4096];  // up to K=512 * 8 rows
  int row0 = blockIdx.x * 8;
  int tid = threadIdx.x;
  for (int i = tid; i < 8 * K; i += 256) {
    int r = i / K, k = i - r * K;
    int r0 = row0 + r;
    size_t addr;
    if (mode == 0) addr = (size_t)r0 * Astride + k;
    else if (mode == 1) {
      int b = r0 >> 9;
      addr = (size_t)(b * TT + selidx[r0]) * Astride + k;
    } else {
      int b = r0 >> 11, t = r0 & (TT - 1);
      addr = (size_t)((b * NHEAD + (k >> 5)) * TT + t) * 32 + (k & 31);
    }
    xT[k * 8 + r] = A[addr];
  }
  __syncthreads();
  for (int c = 0; c < NC; c += 256) {
    int col = c + tid;
    float acc0 = 0, acc1 = 0, acc2 = 0, acc3 = 0, acc4 = 0, acc5 = 0, acc6 = 0, acc7 = 0;
    const float* Wp = W + col;
#pragma unroll 4
    for (int k = 0; k < K; ++k) {
      float w = Wp[(size_t)k * NC];
      const float4 xa = *(const float4*)(xT + k * 8);
      const float4 xb = *(const float4*)(xT + k * 8 + 4);
      acc0 += w * xa.x; acc1 += w * xa.y; acc2 += w * xa.z; acc3 += w * xa.w;
      acc4 += w * xb.x; acc5 += w * xb.y; acc6 += w * xb.z; acc7 += w * xb.w;
    }
    float accs[8] = {acc0, acc1, acc2, acc3, acc4, acc5, acc6, acc7};
#pragma unroll
    for (int r = 0; r < 8; ++r) {
      size_t oi = (size_t)(row0 + r) * OutStride + outOff + col;
      if (obf16) ((ushort*)Out)[oi] = (ushort)f2bf(accs[r]);
      else ((float*)Out)[oi] = accs[r];
    }
  }
}

// ---------------- rope: qtmp in place (f32), kr -> bf16 ----------------
__global__ __launch_bounds__(256) void rope_kernel(const float* __restrict__ cos_t,
                                                   const float* __restrict__ sin_t,
                                                   float* __restrict__ qtmp,
                                                   const float* __restrict__ krtmp,
                                                   ushort* __restrict__ krbf) {
  int row = blockIdx.x, tid = threadIdx.x;
  int t = row & (TT - 1);
  for (int i = tid; i < 544; i += 256) {
    int dd = (i < 512) ? (i & 31) : (i - 512);
    float c = cos_t[t * 32 + dd], s = sin_t[t * 32 + dd];
    if (i < 512) {
      int h = i >> 5;
      float* p0 = qtmp + (size_t)row * 1536 + 512 + h * 64 + dd;
      float xr = p0[0], xi = p0[32];
      p0[0] = xr * c - xi * s;
      p0[32] = xr * s + xi * c;
    } else {
      const float* p0 = krtmp + (size_t)row * 64 + dd;
      float xr = p0[0], xi = p0[32];
      krbf[(size_t)row * 64 + dd] = (ushort)f2bf(xr * c - xi * s);
      krbf[(size_t)row * 64 + dd + 32] = (ushort)f2bf(xr * s + xi * c);
    }
  }
}

// ---------------- gate finalize ----------------
__global__ __launch_bounds__(256) void gate_kernel(const float* __restrict__ gpart,
                                                   const float* __restrict__ b_gate,
                                                   float* __restrict__ bw) {
  int tid = threadIdx.x;  // 256
  float a0 = 0, a1 = 0, a2 = 0, a3 = 0, a4 = 0, a5 = 0;
  for (int r = tid; r < 2 * TT; r += 256) {
    float g0 = gpart[r * 3], g1 = gpart[r * 3 + 1], g2 = gpart[r * 3 + 2];
    if (r < TT) { a0 += g0; a1 += g1; a2 += g2; }
    else { a3 += g0; a4 += g1; a5 += g2; }
  }
  __shared__ float red[6][256];
  red[0][tid] = a0; red[1][tid] = a1; red[2][tid] = a2;
  red[3][tid] = a3; red[4][tid] = a4; red[5][tid] = a5;
  __syncthreads();
  for (int s = 128; s > 0; s >>= 1) {
    if (tid < s) {
#pragma unroll
      for (int q = 0; q < 6; ++q) red[q][tid] += red[q][tid + s];
    }
    __syncthreads();
  }
  if (tid == 0) {
    for (int b = 0; b < 2; ++b) {
      float v[3];
      float mx = -INFINITY;
      for (int j = 0; j < 3; ++j) {
        v[j] = red[b * 3 + j][0] / (float)TT + b_gate[j];
        mx = fmaxf(mx, v[j]);
      }
      float sum = 0.f;
      for (int j = 0; j < 3; ++j) { v[j] = expf(v[j] - mx); sum += v[j]; }
      for (int j = 0; j < 3; ++j) bw[b * 3 + j] = v[j] / sum;
    }
  }
}

// ---------------- top-k (512 of 2048) via bitonic sort ----------------
__global__ __launch_bounds__(1024) void topk_kernel(const float* __restrict__ scores,
                                                    int* __restrict__ selidx) {
  int b = blockIdx.x, tid = threadIdx.x;  // 1024 thr
  __shared__ unsigned long long keys[TT];
  for (int i = tid; i < TT; i += 1024) {
    float s = scores[b * TT + i];
    unsigned u = __float_as_uint(s);
    u = (u & 0x80000000u) ? ~u : (u | 0x80000000u);  // ascending-sortable
    u = ~u;                                          // descending
    keys[i] = ((unsigned long long)u << 32) | (unsigned)i;
  }
  __syncthreads();
  for (int k = 2; k <= TT; k <<= 1) {
    for (int j = k >> 1; j > 0; j >>= 1) {
      for (int i = tid; i < TT; i += 1024) {
        int ixj = i ^ j;
        if (ixj > i) {
          unsigned long long a = keys[i], c = keys[ixj];
          bool sw = ((i & k) == 0) ? (a > c) : (a < c);
          if (sw) { keys[i] = c; keys[ixj] = a; }
        }
      }
      __syncthreads();
    }
  }
  if (tid < 512) selidx[b * 512 + tid] = (int)(keys[tid] & 0xffffffffu);
}

// ---------------- fused MFMA flash attention (cmp + sel + win) ----------------
// 64 Q-rows x 64 K-cols, 4 waves; Q staged once, 3 sources sequential.
// bf16 global K/V; register-prefetch double buffering of K/V staging.
// LDS strides: Qs/Ks 136 shorts (16B rows, 2-way banks), Vts/Ps 72.
__global__ __launch_bounds__(256) void flash_fused_kernel(
    const float* __restrict__ qtmp,
    const ushort* __restrict__ kv,     // [row][kn 512 | v 512] bf16
    const ushort* __restrict__ krbf,   // [row][64] bf16 (roped)
    const ushort* __restrict__ selt,   // [selrow][sk 1536 | sv 512] bf16
    const ushort* __restrict__ wint,   // [row][wk 1536 | wv 512] bf16
    const float* __restrict__ bw,
    float* __restrict__ attout) {
  __shared__ __align__(16) short Qs[64 * 136];
  __shared__ __align__(16) short Ks[64 * 136];
  __shared__ __align__(16) short Vts[32 * 72];
  __shared__ __align__(16) short Ps[4 * 16 * 72];

  int bx = blockIdx.x;
  int qtile = (bx & 1) ? (31 - (bx >> 1)) : (bx >> 1);  // long/short pairing
  int bh = blockIdx.y;
  int b = bh >> 4, h = bh & 15;
  int tid = threadIdx.x;
  int wv = tid >> 6, lane = tid & 63;
  int l15 = lane & 15, quad = lane >> 4;
  const float scale = 0.1020620726159658f;  // 1/sqrt(96)

  int qrow0 = qtile * 64;
  // ---- stage Q (64 x 96) -> bf16 once ----
  for (int i = tid; i < 64 * 48; i += 256) {
    int qi = i / 48, dp = (i - qi * 48) * 2;
    int col = (dp < 32) ? (h * 32 + dp) : (512 + h * 64 + (dp - 32));
    const float2 q2 = *(const float2*)(qtmp + (size_t)(b * TT + qrow0 + qi) * 1536 + col);
    *(unsigned*)(Qs + qi * 136 + dp) = pack2bf(q2.x * scale, q2.y * scale);
  }

  f32x4 oacc[2];
  oacc[0] = (f32x4){0.f, 0.f, 0.f, 0.f};
  oacc[1] = (f32x4){0.f, 0.f, 0.f, 0.f};

  ushort4 kpre[6], vpre[2];

  for (int s = 0; s < 3; ++s) {
    // ---- per-source parameters ----
    const ushort *kb1, *kb2, *vb;
    size_t krs1, krs2, vrs;
    int split, Tk, causal;
    if (s == 0) {  // cmp
      kb1 = kv + h * 32;        krs1 = 1024; split = 32;
      kb2 = krbf;               krs2 = 64;
      vb = kv + 512 + h * 32;   vrs = 1024;
      Tk = TT; causal = 1;
    } else if (s == 1) {  // sel
      kb1 = selt + h * 96;      krs1 = 2048; split = 96;
      kb2 = selt;               krs2 = 2048;
      vb = selt + 1536 + h * 32; vrs = 2048;
      Tk = 512; causal = 0;
    } else {  // win
      kb1 = wint + h * 96;      krs1 = 2048; split = 96;
      kb2 = wint;               krs2 = 2048;
      vb = wint + 1536 + h * 32; vrs = 2048;
      Tk = TT; causal = 1;
    }
    size_t bTk = (size_t)b * Tk;

    auto prefetch = [&](int kt) {
      int krow0 = kt * 64;
#pragma unroll
      for (int c = 0; c < 6; ++c) {
        int i = c * 256 + tid;
        int kj = i / 24, dp = (i - kj * 24) * 4;
        const ushort* src = (dp < split)
                                ? kb1 + (bTk + krow0 + kj) * krs1 + dp
                                : kb2 + (bTk + krow0 + kj) * krs2 + (dp - split);
        kpre[c] = *(const ushort4*)src;
      }
#pragma unroll
      for (int c = 0; c < 2; ++c) {
        int i = c * 256 + tid;
        int kj = i >> 3, d0 = (i & 7) * 4;
        vpre[c] = *(const ushort4*)(vb + (bTk + krow0 + kj) * vrs + d0);
      }
    };
    auto commit = [&]() {
#pragma unroll
      for (int c = 0; c < 6; ++c) {
        int i = c * 256 + tid;
        int kj = i / 24, dp = (i - kj * 24) * 4;
        *(ushort4*)(Ks + kj * 136 + dp) = kpre[c];
      }
#pragma unroll
      for (int c = 0; c < 2; ++c) {
        int i = c * 256 + tid;
        int kj = i >> 3, d0 = (i & 7) * 4;
        ushort4 v4 = vpre[c];
        Vts[(d0 + 0) * 72 + kj] = (short)v4.x;
        Vts[(d0 + 1) * 72 + kj] = (short)v4.y;
        Vts[(d0 + 2) * 72 + kj] = (short)v4.z;
        Vts[(d0 + 3) * 72 + kj] = (short)v4.w;
      }
    };

    float m[4], l[4];
    f32x4 of[2];
#pragma unroll
    for (int i = 0; i < 4; ++i) { m[i] = -INFINITY; l[i] = 0.f; }
    of[0] = (f32x4){0.f, 0.f, 0.f, 0.f};
    of[1] = (f32x4){0.f, 0.f, 0.f, 0.f};

    int nkt = causal ? (qtile + 1) : (Tk >> 6);
    prefetch(0);
    for (int kt = 0; kt < nkt; ++kt) {
      __syncthreads();  // prior LDS reads (or Q staging) complete
      commit();
      __syncthreads();
      if (kt + 1 < nkt) prefetch(kt + 1);
      int krow0 = kt * 64;

      // ---- S = Q K^T ----
      f32x4 sf[4];
#pragma unroll
      for (int nb = 0; nb < 4; ++nb) sf[nb] = (f32x4){0.f, 0.f, 0.f, 0.f};
#pragma unroll
      for (int ks = 0; ks < 3; ++ks) {
        bf16x8 aq = *(const bf16x8*)(Qs + (wv * 16 + l15) * 136 + ks * 32 + quad * 8);
#pragma unroll
        for (int nb = 0; nb < 4; ++nb) {
          bf16x8 bk = *(const bf16x8*)(Ks + (nb * 16 + l15) * 136 + ks * 32 + quad * 8);
          sf[nb] = __builtin_amdgcn_mfma_f32_16x16x32_bf16(aq, bk, sf[nb], 0, 0, 0);
        }
      }
      // C-layout: sf[nb][reg] = S[quad*4+reg][nb*16+l15]
      if (causal && kt == qtile) {
        int rowg = qrow0 + wv * 16 + quad * 4;
#pragma unroll
        for (int reg = 0; reg < 4; ++reg) {
#pragma unroll
          for (int nb = 0; nb < 4; ++nb) {
            int colg = krow0 + nb * 16 + l15;
            if (colg > rowg + reg) sf[nb][reg] = -INFINITY;
          }
        }
      }
      // ---- online softmax ----
      short* Pw = Ps + wv * 16 * 72;
#pragma unroll
      for (int reg = 0; reg < 4; ++reg) {
        float mx = fmaxf(fmaxf(sf[0][reg], sf[1][reg]), fmaxf(sf[2][reg], sf[3][reg]));
#pragma unroll
        for (int off = 8; off > 0; off >>= 1) mx = fmaxf(mx, __shfl_xor(mx, off, 64));
        float mn = fmaxf(m[reg], mx);
        float alpha = __expf(m[reg] - mn);
        m[reg] = mn;
        float ps = 0.f;
#pragma unroll
        for (int nb = 0; nb < 4; ++nb) {
          float p = __expf(sf[nb][reg] - mn);
          ps += p;
          Pw[(quad * 4 + reg) * 72 + nb * 16 + l15] = f2bf(p);
        }
#pragma unroll
        for (int off = 8; off > 0; off >>= 1) ps += __shfl_xor(ps, off, 64);
        l[reg] = l[reg] * alpha + ps;
        of[0][reg] *= alpha;
        of[1][reg] *= alpha;
      }
      // wave-private P: in-wave LDS ordering only
      asm volatile("s_waitcnt lgkmcnt(0)" ::: "memory");

      // ---- O += P V ----
#pragma unroll
      for (int ks2 = 0; ks2 < 2; ++ks2) {
        bf16x8 ap = *(const bf16x8*)(Pw + l15 * 72 + ks2 * 32 + quad * 8);
#pragma unroll
        for (int vn = 0; vn < 2; ++vn) {
          bf16x8 bv = *(const bf16x8*)(Vts + (vn * 16 + l15) * 72 + ks2 * 32 + quad * 8);
          of[vn] = __builtin_amdgcn_mfma_f32_16x16x32_bf16(ap, bv, of[vn], 0, 0, 0);
        }
      }
    }

    float wgt = bw[b * 3 + s];
#pragma unroll
    for (int reg = 0; reg < 4; ++reg) {
      float inv = wgt / l[reg];
      oacc[0][reg] += of[0][reg] * inv;
      oacc[1][reg] += of[1][reg] * inv;
    }
  }

  // ---- epilogue (single write) ----
#pragma unroll
  for (int reg = 0; reg < 4; ++reg) {
    int trow = qrow0 + wv * 16 + quad * 4 + reg;
#pragma unroll
    for (int vn = 0; vn < 2; ++vn) {
      attout[(size_t)(bh * TT + trow) * 32 + vn * 16 + l15] = oacc[vn][reg];
    }
  }
}

// ---------------- launch ----------------
extern "C" void kernel_launch(void* const* d_in, const int* in_sizes, int n_in,
                              void* d_out, int out_size, void* d_ws, size_t ws_size,
                              hipStream_t stream) {
  const float* x      = (const float*)d_in[0];
  const float* W_cq   = (const float*)d_in[1];
  const float* qnw    = (const float*)d_in[2];
  const float* W_dqn  = (const float*)d_in[3];
  const float* W_dqr  = (const float*)d_in[4];
  const float* W_ckv  = (const float*)d_in[5];
  const float* kvnw   = (const float*)d_in[6];
  const float* W_dkn  = (const float*)d_in[7];
  const float* W_dv   = (const float*)d_in[8];
  const float* W_kr   = (const float*)d_in[9];
  const float* W_imp  = (const float*)d_in[10];
  const float* b_imp  = (const float*)d_in[11];
  const float* W_selk = (const float*)d_in[12];
  const float* W_selv = (const float*)d_in[13];
  const float* W_wink = (const float*)d_in[14];
  const float* W_winv = (const float*)d_in[15];
  const float* W_gate = (const float*)d_in[16];
  const float* b_gate = (const float*)d_in[17];
  const float* W_proj = (const float*)d_in[18];
  const float* cos_f  = (const float*)d_in[19];
  const float* sin_f  = (const float*)d_in[20];
  float* out = (float*)d_out;
  float* ws  = (float*)d_ws;

  size_t off = 0;
  auto alloc = [&](size_t n) {
    float* p = ws + off;
    off += (n + 255) & ~(size_t)255;
    return p;
  };
  const int ROWS = 2 * TT;  // 4096
  float* xh      = alloc((size_t)ROWS * 256);
  float* nq      = alloc((size_t)ROWS * 96);
  float* qtmp    = alloc((size_t)ROWS * 1536);
  float* nkv     = alloc((size_t)ROWS * 32);
  ushort* kvtmp  = (ushort*)alloc((size_t)ROWS * 512);   // bf16 [kn 512 | v 512]
  float* krtmp   = alloc((size_t)ROWS * 64);
  ushort* krbf   = (ushort*)alloc((size_t)ROWS * 32);    // bf16 roped kr
  float* scores  = alloc(ROWS);
  float* gpart   = alloc((size_t)ROWS * 3);
  float* bwp     = alloc(8);
  int* selidx    = (int*)alloc(1024);
  ushort* seltmp = (ushort*)alloc((size_t)1024 * 1024);  // bf16 [sk 1536 | sv 512]
  ushort* wintmp = (ushort*)alloc((size_t)ROWS * 1024);  // bf16 [wk 1536 | wv 512]
  float* attout  = alloc((size_t)32 * TT * 32);

  logmap_kernel<<<ROWS, 256, 0, stream>>>(x, xh);
  nq_kernel<<<ROWS, 128, 0, stream>>>(xh, W_cq, qnw, nq);
  proj8_kernel<<<ROWS / 8, 256, 0, stream>>>(nq, W_dqn, qtmp, nullptr, 96, 512, 96, 1536, 0, 0, 0);
  proj8_kernel<<<ROWS / 8, 256, 0, stream>>>(nq, W_dqr, qtmp, nullptr, 96, 1024, 96, 1536, 512, 0, 0);
  nkv_kernel<<<ROWS, 128, 0, stream>>>(x, W_ckv, kvnw, W_imp, b_imp, W_gate, W_kr,
                                       nkv, scores, gpart, krtmp);
  proj8_kernel<<<ROWS / 8, 256, 0, stream>>>(nkv, W_dkn, kvtmp, nullptr, 32, 512, 32, 1024, 0, 0, 1);
  proj8_kernel<<<ROWS / 8, 256, 0, stream>>>(nkv, W_dv, kvtmp, nullptr, 32, 512, 32, 1024, 512, 0, 1);
  rope_kernel<<<ROWS, 256, 0, stream>>>(cos_f, sin_f, qtmp, krtmp, krbf);
  gate_kernel<<<1, 256, 0, stream>>>(gpart, b_gate, bwp);
  topk_kernel<<<2, 1024, 0, stream>>>(scores, selidx);
  proj8_kernel<<<128, 256, 0, stream>>>(x, W_selk, seltmp, selidx, 256, 1536, 256, 2048, 0, 1, 1);
  proj8_kernel<<<128, 256, 0, stream>>>(x, W_selv, seltmp, selidx, 256, 512, 256, 2048, 1536, 1, 1);
  proj8_kernel<<<ROWS / 8, 256, 0, stream>>>(x, W_wink, wintmp, nullptr, 256, 1536, 256, 2048, 0, 0, 1);
  proj8_kernel<<<ROWS / 8, 256, 0, stream>>>(x, W_winv, wintmp, nullptr, 256, 512, 256, 2048, 1536, 0, 1);

  dim3 fg(32, 32);
  flash_fused_kernel<<<fg, 256, 0, stream>>>(qtmp, kvtmp, krbf, seltmp, wintmp, bwp, attout);

  proj8_kernel<<<ROWS / 8, 256, 0, stream>>>(attout, W_proj, out, nullptr, 512, 256, 0, 256, 0, 2, 0);
}

// Round 5
// 485.723 us; speedup vs baseline: 6.1391x; 2.0342x over previous
//
#include <hip/hip_runtime.h>
#include <hip/hip_bf16.h>
#include <math.h>

#define TT 2048
#define NE 256
#define NHEAD 16

typedef __attribute__((ext_vector_type(8))) short bf16x8;
typedef __attribute__((ext_vector_type(4))) float f32x4;
typedef unsigned short ushort;
typedef __attribute__((ext_vector_type(8))) unsigned short us8;

__device__ __forceinline__ short f2bf(float x) {
  __hip_bfloat16 h = __float2bfloat16(x);
  return *reinterpret_cast<short*>(&h);
}
__device__ __forceinline__ unsigned pack2bf(float a, float b) {
  return (unsigned)(ushort)f2bf(a) | ((unsigned)(ushort)f2bf(b) << 16);
}

// ---------------- block reduce (256 threads) ----------------
__device__ __forceinline__ float blk_sum(float v, float* red, int tid) {
#pragma unroll
  for (int off = 32; off > 0; off >>= 1) v += __shfl_down(v, off, 64);
  __syncthreads();
  if ((tid & 63) == 0) red[tid >> 6] = v;
  __syncthreads();
  return red[0] + red[1] + red[2] + red[3];
}

// ---------------- 1. logmap (+ x -> bf16 copy) ----------------
__global__ __launch_bounds__(256) void logmap_kernel(const float* __restrict__ x,
                                                     float* __restrict__ xh,
                                                     ushort* __restrict__ xbf) {
  __shared__ float red[4];
  int row = blockIdx.x, tid = threadIdx.x;
  int t = row & (TT - 1);
  float uv = x[row * NE + tid];
  float rv = (t == 0) ? 0.f : x[row * NE - NE + tid];
  xbf[row * NE + tid] = (ushort)f2bf(uv);
  float xn2 = blk_sum(rv * rv, red, tid);
  float un2 = blk_sum(uv * uv, red, tid);
  float ip  = blk_sum(-rv * uv, red, tid);
  float den = 1.f + 2.f * ip + xn2 * un2;
  float mob = ((1.f + 2.f * ip + un2) * (-rv) + (1.f - xn2) * uv) / den;
  float an2 = blk_sum(mob * mob, red, tid);
  float an = sqrtf(an2);
  float cf = 1.f + xn2;
  float arg = fminf(sqrtf(an), 0.999f);
  xh[row * NE + tid] = cf * atanhf(arg) * mob / an;
}

// ---------------- 2. nq = rmsnorm(xh @ W_cq) -> bf16 ----------------
__global__ __launch_bounds__(128) void nq_kernel(const float* __restrict__ xh,
                                                 const float* __restrict__ W_cq,
                                                 const float* __restrict__ qnw,
                                                 ushort* __restrict__ nqb) {
  int row = blockIdx.x, tid = threadIdx.x;  // 128 thr
  __shared__ float xr[256];
  __shared__ float red[128];
  xr[tid] = xh[row * 256 + tid];
  xr[tid + 128] = xh[row * 256 + tid + 128];
  __syncthreads();
  float acc = 0.f;
  if (tid < 96) {
    const float* wp = W_cq + tid;
#pragma unroll 4
    for (int k = 0; k < 256; ++k) acc += xr[k] * wp[k * 96];
  }
  red[tid] = (tid < 96) ? acc * acc : 0.f;
  __syncthreads();
  for (int s = 64; s > 0; s >>= 1) {
    if (tid < s) red[tid] += red[tid + s];
    __syncthreads();
  }
  float sc = rsqrtf(red[0] / 96.f + 1e-6f);
  if (tid < 96) nqb[row * 96 + tid] = (ushort)f2bf(acc * sc * qnw[tid]);
}

// ---------------- 3. nkv(bf16) + imp scores + gate partials + kr ----------------
__global__ __launch_bounds__(128) void nkv_kernel(const float* __restrict__ x,
                                                  const float* __restrict__ W_ckv,
                                                  const float* __restrict__ kvnw,
                                                  const float* __restrict__ W_imp,
                                                  const float* __restrict__ b_imp,
                                                  const float* __restrict__ W_gate,
                                                  const float* __restrict__ W_kr,
                                                  ushort* __restrict__ nkvb,
                                                  float* __restrict__ scores,
                                                  float* __restrict__ gpart,
                                                  float* __restrict__ krtmp) {
  int row = blockIdx.x, tid = threadIdx.x;  // 128 thr
  __shared__ float xr[256];
  xr[tid] = x[row * 256 + tid];
  xr[tid + 128] = x[row * 256 + tid + 128];
  __syncthreads();
  const float* wp;
  int stride;
  if (tid < 32) { wp = W_ckv + tid; stride = 32; }
  else if (tid == 32) { wp = W_imp; stride = 1; }
  else if (tid < 36) { wp = W_gate + (tid - 33); stride = 3; }
  else if (tid < 100) { wp = W_kr + (tid - 36); stride = 64; }
  else { wp = W_ckv; stride = 0; }
  float acc = 0.f;
#pragma unroll 4
  for (int k = 0; k < 256; ++k) acc += xr[k] * wp[k * stride];
  float ss = acc * acc;
#pragma unroll
  for (int off = 16; off > 0; off >>= 1) ss += __shfl_xor(ss, off, 64);
  if (tid < 32) {
    float sc = rsqrtf(ss / 32.f + 1e-6f);
    nkvb[row * 32 + tid] = (ushort)f2bf(acc * sc * kvnw[tid]);
  } else if (tid == 32) {
    scores[row] = acc + b_imp[0];
  } else if (tid < 36) {
    gpart[row * 3 + (tid - 33)] = acc;
  } else if (tid < 100) {
    krtmp[row * 64 + (tid - 36)] = acc;
  }
}

// ---------------- weight convert: W(f32 [K][N]) -> Wt(bf16 [N][K]) ----------------
__global__ __launch_bounds__(256) void wtconv_kernel(const float* __restrict__ W1,
                                                     const float* __restrict__ W2,
                                                     ushort* __restrict__ Wt,
                                                     int N1, int N, int K) {
  int i = blockIdx.x * 256 + threadIdx.x;
  if (i >= N * K) return;
  int n = i / K, k = i - n * K;
  float v = (n < N1) ? W1[(size_t)k * N1 + n] : W2[(size_t)k * (N - N1) + (n - N1)];
  Wt[i] = (ushort)f2bf(v);
}

// ---------------- bf16 MFMA GEMM: D[m][n] = sum_k A[m][k] * Wt[n][k] ----------------
// 128x128 tile, BK=32, 4 waves (2x2 of 64x64). A stride K, Wt stride K.
// Staging: 2 threads/row, each thread covers 16 contiguous shorts via TWO us8
// (us8 = 8 ushorts = 16 B; one was the round-4 NaN bug).
__global__ __launch_bounds__(256) void gemm_kernel(const ushort* __restrict__ A,
                                                   const ushort* __restrict__ Bt,
                                                   void* __restrict__ Out,
                                                   const int* __restrict__ selidx,
                                                   int K, int ldo, int obf16) {
  __shared__ __align__(16) short As[128 * 40];
  __shared__ __align__(16) short Bs[128 * 40];
  int m0 = blockIdx.x * 128, n0 = blockIdx.y * 128;
  int tid = threadIdx.x;
  int wv = tid >> 6, lane = tid & 63;
  int l15 = lane & 15, quad = lane >> 4;
  int wm = wv >> 1, wn = wv & 1;

  int r = tid >> 1, seg = tid & 1;
  int arow = m0 + r;
  if (selidx) arow = ((arow >> 9) * TT) + selidx[m0 + r];
  const ushort* ga = A + (size_t)arow * K + seg * 16;
  const ushort* gb = Bt + (size_t)(n0 + r) * K + seg * 16;

  f32x4 acc[4][4];
#pragma unroll
  for (int i = 0; i < 4; ++i)
#pragma unroll
    for (int j = 0; j < 4; ++j) acc[i][j] = (f32x4){0.f, 0.f, 0.f, 0.f};

  int nk = K >> 5;
  us8 apre0 = *(const us8*)ga, apre1 = *(const us8*)(ga + 8);
  us8 bpre0 = *(const us8*)gb, bpre1 = *(const us8*)(gb + 8);
  for (int kk = 0; kk < nk; ++kk) {
    __syncthreads();
    *(us8*)(As + r * 40 + seg * 16) = apre0;
    *(us8*)(As + r * 40 + seg * 16 + 8) = apre1;
    *(us8*)(Bs + r * 40 + seg * 16) = bpre0;
    *(us8*)(Bs + r * 40 + seg * 16 + 8) = bpre1;
    __syncthreads();
    if (kk + 1 < nk) {
      apre0 = *(const us8*)(ga + (kk + 1) * 32);
      apre1 = *(const us8*)(ga + (kk + 1) * 32 + 8);
      bpre0 = *(const us8*)(gb + (kk + 1) * 32);
      bpre1 = *(const us8*)(gb + (kk + 1) * 32 + 8);
    }
    bf16x8 af[4], bf[4];
#pragma unroll
    for (int mf = 0; mf < 4; ++mf)
      af[mf] = *(const bf16x8*)(As + (wm * 64 + mf * 16 + l15) * 40 + quad * 8);
#pragma unroll
    for (int nf = 0; nf < 4; ++nf)
      bf[nf] = *(const bf16x8*)(Bs + (wn * 64 + nf * 16 + l15) * 40 + quad * 8);
#pragma unroll
    for (int mf = 0; mf < 4; ++mf)
#pragma unroll
      for (int nf = 0; nf < 4; ++nf)
        acc[mf][nf] = __builtin_amdgcn_mfma_f32_16x16x32_bf16(af[mf], bf[nf], acc[mf][nf], 0, 0, 0);
  }

#pragma unroll
  for (int mf = 0; mf < 4; ++mf) {
#pragma unroll
    for (int nf = 0; nf < 4; ++nf) {
#pragma unroll
      for (int reg = 0; reg < 4; ++reg) {
        int row = m0 + wm * 64 + mf * 16 + quad * 4 + reg;
        int col = n0 + wn * 64 + nf * 16 + l15;
        size_t oi = (size_t)row * ldo + col;
        float v = acc[mf][nf][reg];
        if (obf16) ((ushort*)Out)[oi] = (ushort)f2bf(v);
        else ((float*)Out)[oi] = v;
      }
    }
  }
}

// ---------------- rope: qtmp in place (f32), kr -> bf16 ----------------
__global__ __launch_bounds__(256) void rope_kernel(const float* __restrict__ cos_t,
                                                   const float* __restrict__ sin_t,
                                                   float* __restrict__ qtmp,
                                                   const float* __restrict__ krtmp,
                                                   ushort* __restrict__ krbf) {
  int row = blockIdx.x, tid = threadIdx.x;
  int t = row & (TT - 1);
  for (int i = tid; i < 544; i += 256) {
    int dd = (i < 512) ? (i & 31) : (i - 512);
    float c = cos_t[t * 32 + dd], s = sin_t[t * 32 + dd];
    if (i < 512) {
      int h = i >> 5;
      float* p0 = qtmp + (size_t)row * 1536 + 512 + h * 64 + dd;
      float xr = p0[0], xi = p0[32];
      p0[0] = xr * c - xi * s;
      p0[32] = xr * s + xi * c;
    } else {
      const float* p0 = krtmp + (size_t)row * 64 + dd;
      float xr = p0[0], xi = p0[32];
      krbf[(size_t)row * 64 + dd] = (ushort)f2bf(xr * c - xi * s);
      krbf[(size_t)row * 64 + dd + 32] = (ushort)f2bf(xr * s + xi * c);
    }
  }
}

// ---------------- gate finalize ----------------
__global__ __launch_bounds__(256) void gate_kernel(const float* __restrict__ gpart,
                                                   const float* __restrict__ b_gate,
                                                   float* __restrict__ bw) {
  int tid = threadIdx.x;  // 256
  float a0 = 0, a1 = 0, a2 = 0, a3 = 0, a4 = 0, a5 = 0;
  for (int r = tid; r < 2 * TT; r += 256) {
    float g0 = gpart[r * 3], g1 = gpart[r * 3 + 1], g2 = gpart[r * 3 + 2];
    if (r < TT) { a0 += g0; a1 += g1; a2 += g2; }
    else { a3 += g0; a4 += g1; a5 += g2; }
  }
  __shared__ float red[6][256];
  red[0][tid] = a0; red[1][tid] = a1; red[2][tid] = a2;
  red[3][tid] = a3; red[4][tid] = a4; red[5][tid] = a5;
  __syncthreads();
  for (int s = 128; s > 0; s >>= 1) {
    if (tid < s) {
#pragma unroll
      for (int q = 0; q < 6; ++q) red[q][tid] += red[q][tid + s];
    }
    __syncthreads();
  }
  if (tid == 0) {
    for (int b = 0; b < 2; ++b) {
      float v[3];
      float mx = -INFINITY;
      for (int j = 0; j < 3; ++j) {
        v[j] = red[b * 3 + j][0] / (float)TT + b_gate[j];
        mx = fmaxf(mx, v[j]);
      }
      float sum = 0.f;
      for (int j = 0; j < 3; ++j) { v[j] = expf(v[j] - mx); sum += v[j]; }
      for (int j = 0; j < 3; ++j) bw[b * 3 + j] = v[j] / sum;
    }
  }
}

// ---------------- top-k (512 of 2048) via bitonic sort ----------------
__global__ __launch_bounds__(1024) void topk_kernel(const float* __restrict__ scores,
                                                    int* __restrict__ selidx) {
  int b = blockIdx.x, tid = threadIdx.x;  // 1024 thr
  __shared__ unsigned long long keys[TT];
  for (int i = tid; i < TT; i += 1024) {
    float s = scores[b * TT + i];
    unsigned u = __float_as_uint(s);
    u = (u & 0x80000000u) ? ~u : (u | 0x80000000u);  // ascending-sortable
    u = ~u;                                          // descending
    keys[i] = ((unsigned long long)u << 32) | (unsigned)i;
  }
  __syncthreads();
  for (int k = 2; k <= TT; k <<= 1) {
    for (int j = k >> 1; j > 0; j >>= 1) {
      for (int i = tid; i < TT; i += 1024) {
        int ixj = i ^ j;
        if (ixj > i) {
          unsigned long long a = keys[i], c = keys[ixj];
          bool sw = ((i & k) == 0) ? (a > c) : (a < c);
          if (sw) { keys[i] = c; keys[ixj] = a; }
        }
      }
      __syncthreads();
    }
  }
  if (tid < 512) selidx[b * 512 + tid] = (int)(keys[tid] & 0xffffffffu);
}

// ---------------- fused MFMA flash attention (cmp + sel + win) ----------------
// No-max softmax (scores tiny; clamp 30 as insurance), l via ones-MFMA.
// LDS strides: Qs/Ks 104, Vts 72, Ps 72 -> 40448 B -> 4 blocks/CU.
__global__ __launch_bounds__(256) void flash_fused_kernel(
    const float* __restrict__ qtmp,
    const ushort* __restrict__ kv,     // [row][kn 512 | v 512] bf16
    const ushort* __restrict__ krbf,   // [row][64] bf16 (roped)
    const ushort* __restrict__ selt,   // [selrow][sk 1536 | sv 512] bf16
    const ushort* __restrict__ wint,   // [row][wk 1536 | wv 512] bf16
    const float* __restrict__ bw,
    ushort* __restrict__ attout) {     // [b*TT+t][h*32+d] bf16
  __shared__ __align__(16) short Qs[64 * 104];
  __shared__ __align__(16) short Ks[64 * 104];
  __shared__ __align__(16) short Vts[32 * 72];
  __shared__ __align__(16) short Ps[4 * 16 * 72];

  int bx = blockIdx.x;
  int qtile = (bx & 1) ? (31 - (bx >> 1)) : (bx >> 1);  // long/short pairing
  int bh = blockIdx.y;
  int b = bh >> 4, h = bh & 15;
  int tid = threadIdx.x;
  int wv = tid >> 6, lane = tid & 63;
  int l15 = lane & 15, quad = lane >> 4;
  const float scale = 0.1020620726159658f;  // 1/sqrt(96)
  const bf16x8 onesf = {16256, 16256, 16256, 16256, 16256, 16256, 16256, 16256};

  int qrow0 = qtile * 64;
  // ---- stage Q (64 x 96) -> bf16 once ----
  for (int i = tid; i < 64 * 48; i += 256) {
    int qi = i / 48, dp = (i - qi * 48) * 2;
    int col = (dp < 32) ? (h * 32 + dp) : (512 + h * 64 + (dp - 32));
    const float2 q2 = *(const float2*)(qtmp + (size_t)(b * TT + qrow0 + qi) * 1536 + col);
    *(unsigned*)(Qs + qi * 104 + dp) = pack2bf(q2.x * scale, q2.y * scale);
  }

  f32x4 oacc[2];
  oacc[0] = (f32x4){0.f, 0.f, 0.f, 0.f};
  oacc[1] = (f32x4){0.f, 0.f, 0.f, 0.f};

  ushort4 kpre[6], vpre[2];

  for (int s = 0; s < 3; ++s) {
    const ushort *kb1, *kb2, *vb;
    size_t krs1, krs2, vrs;
    int split, Tk, causal;
    if (s == 0) {  // cmp
      kb1 = kv + h * 32;        krs1 = 1024; split = 32;
      kb2 = krbf;               krs2 = 64;
      vb = kv + 512 + h * 32;   vrs = 1024;
      Tk = TT; causal = 1;
    } else if (s == 1) {  // sel
      kb1 = selt + h * 96;      krs1 = 2048; split = 96;
      kb2 = selt;               krs2 = 2048;
      vb = selt + 1536 + h * 32; vrs = 2048;
      Tk = 512; causal = 0;
    } else {  // win
      kb1 = wint + h * 96;      krs1 = 2048; split = 96;
      kb2 = wint;               krs2 = 2048;
      vb = wint + 1536 + h * 32; vrs = 2048;
      Tk = TT; causal = 1;
    }
    size_t bTk = (size_t)b * Tk;

    auto prefetch = [&](int kt) {
      int krow0 = kt * 64;
#pragma unroll
      for (int c = 0; c < 6; ++c) {
        int i = c * 256 + tid;
        int kj = i / 24, dp = (i - kj * 24) * 4;
        const ushort* src = (dp < split)
                                ? kb1 + (bTk + krow0 + kj) * krs1 + dp
                                : kb2 + (bTk + krow0 + kj) * krs2 + (dp - split);
        kpre[c] = *(const ushort4*)src;
      }
#pragma unroll
      for (int c = 0; c < 2; ++c) {
        int i = c * 256 + tid;
        int kj = i >> 3, d0 = (i & 7) * 4;
        vpre[c] = *(const ushort4*)(vb + (bTk + krow0 + kj) * vrs + d0);
      }
    };
    auto commit = [&]() {
#pragma unroll
      for (int c = 0; c < 6; ++c) {
        int i = c * 256 + tid;
        int kj = i / 24, dp = (i - kj * 24) * 4;
        *(ushort4*)(Ks + kj * 104 + dp) = kpre[c];
      }
#pragma unroll
      for (int c = 0; c < 2; ++c) {
        int i = c * 256 + tid;
        int kj = i >> 3, d0 = (i & 7) * 4;
        ushort4 v4 = vpre[c];
        Vts[(d0 + 0) * 72 + kj] = (short)v4.x;
        Vts[(d0 + 1) * 72 + kj] = (short)v4.y;
        Vts[(d0 + 2) * 72 + kj] = (short)v4.z;
        Vts[(d0 + 3) * 72 + kj] = (short)v4.w;
      }
    };

    f32x4 of[2], lf;
    of[0] = (f32x4){0.f, 0.f, 0.f, 0.f};
    of[1] = (f32x4){0.f, 0.f, 0.f, 0.f};
    lf = (f32x4){0.f, 0.f, 0.f, 0.f};

    int nkt = causal ? (qtile + 1) : (Tk >> 6);
    prefetch(0);
    for (int kt = 0; kt < nkt; ++kt) {
      __syncthreads();  // prior LDS reads (or Q staging) complete
      commit();
      __syncthreads();
      if (kt + 1 < nkt) prefetch(kt + 1);
      int krow0 = kt * 64;

      // ---- S = Q K^T ----
      f32x4 sf[4];
#pragma unroll
      for (int nb = 0; nb < 4; ++nb) sf[nb] = (f32x4){0.f, 0.f, 0.f, 0.f};
#pragma unroll
      for (int ks = 0; ks < 3; ++ks) {
        bf16x8 aq = *(const bf16x8*)(Qs + (wv * 16 + l15) * 104 + ks * 32 + quad * 8);
#pragma unroll
        for (int nb = 0; nb < 4; ++nb) {
          bf16x8 bk = *(const bf16x8*)(Ks + (nb * 16 + l15) * 104 + ks * 32 + quad * 8);
          sf[nb] = __builtin_amdgcn_mfma_f32_16x16x32_bf16(aq, bk, sf[nb], 0, 0, 0);
        }
      }
      // C-layout: sf[nb][reg] = S[quad*4+reg][nb*16+l15]
      if (causal && kt == qtile) {
        int rowg = qrow0 + wv * 16 + quad * 4;
#pragma unroll
        for (int reg = 0; reg < 4; ++reg) {
#pragma unroll
          for (int nb = 0; nb < 4; ++nb) {
            int colg = krow0 + nb * 16 + l15;
            if (colg > rowg + reg) sf[nb][reg] = -INFINITY;
          }
        }
      }
      // ---- no-max softmax: p = exp(min(s,30)); scores are O(1) so exact ----
      short* Pw = Ps + wv * 16 * 72;
#pragma unroll
      for (int nb = 0; nb < 4; ++nb) {
#pragma unroll
        for (int reg = 0; reg < 4; ++reg) {
          float p = __expf(fminf(sf[nb][reg], 30.f));
          Pw[(quad * 4 + reg) * 72 + nb * 16 + l15] = f2bf(p);
        }
      }
      // wave-private P: in-wave LDS ordering only
      asm volatile("s_waitcnt lgkmcnt(0)" ::: "memory");

      // ---- O += P V, l += P * ones ----
#pragma unroll
      for (int ks2 = 0; ks2 < 2; ++ks2) {
        bf16x8 ap = *(const bf16x8*)(Pw + l15 * 72 + ks2 * 32 + quad * 8);
        lf = __builtin_amdgcn_mfma_f32_16x16x32_bf16(ap, onesf, lf, 0, 0, 0);
#pragma unroll
        for (int vn = 0; vn < 2; ++vn) {
          bf16x8 bv = *(const bf16x8*)(Vts + (vn * 16 + l15) * 72 + ks2 * 32 + quad * 8);
          of[vn] = __builtin_amdgcn_mfma_f32_16x16x32_bf16(ap, bv, of[vn], 0, 0, 0);
        }
      }
    }

    float wgt = bw[b * 3 + s];
#pragma unroll
    for (int reg = 0; reg < 4; ++reg) {
      float inv = wgt / lf[reg];
      oacc[0][reg] += of[0][reg] * inv;
      oacc[1][reg] += of[1][reg] * inv;
    }
  }

  // ---- epilogue: bf16, [b*TT+t][h*32+d] ----
#pragma unroll
  for (int reg = 0; reg < 4; ++reg) {
    int trow = qrow0 + wv * 16 + quad * 4 + reg;
#pragma unroll
    for (int vn = 0; vn < 2; ++vn) {
      attout[(size_t)(b * TT + trow) * 512 + h * 32 + vn * 16 + l15] =
          (ushort)f2bf(oacc[vn][reg]);
    }
  }
}

// ---------------- launch ----------------
extern "C" void kernel_launch(void* const* d_in, const int* in_sizes, int n_in,
                              void* d_out, int out_size, void* d_ws, size_t ws_size,
                              hipStream_t stream) {
  const float* x      = (const float*)d_in[0];
  const float* W_cq   = (const float*)d_in[1];
  const float* qnw    = (const float*)d_in[2];
  const float* W_dqn  = (const float*)d_in[3];
  const float* W_dqr  = (const float*)d_in[4];
  const float* W_ckv  = (const float*)d_in[5];
  const float* kvnw   = (const float*)d_in[6];
  const float* W_dkn  = (const float*)d_in[7];
  const float* W_dv   = (const float*)d_in[8];
  const float* W_kr   = (const float*)d_in[9];
  const float* W_imp  = (const float*)d_in[10];
  const float* b_imp  = (const float*)d_in[11];
  const float* W_selk = (const float*)d_in[12];
  const float* W_selv = (const float*)d_in[13];
  const float* W_wink = (const float*)d_in[14];
  const float* W_winv = (const float*)d_in[15];
  const float* W_gate = (const float*)d_in[16];
  const float* b_gate = (const float*)d_in[17];
  const float* W_proj = (const float*)d_in[18];
  const float* cos_f  = (const float*)d_in[19];
  const float* sin_f  = (const float*)d_in[20];
  float* out = (float*)d_out;
  float* ws  = (float*)d_ws;

  size_t off = 0;
  auto alloc = [&](size_t n) {
    float* p = ws + off;
    off += (n + 255) & ~(size_t)255;
    return p;
  };
  const int ROWS = 2 * TT;  // 4096
  float* xh       = alloc((size_t)ROWS * 256);
  ushort* xbf     = (ushort*)alloc((size_t)ROWS * 128);
  ushort* nqb     = (ushort*)alloc((size_t)ROWS * 48);
  float* qtmp     = alloc((size_t)ROWS * 1536);
  ushort* nkvb    = (ushort*)alloc((size_t)ROWS * 16);
  ushort* kvtmp   = (ushort*)alloc((size_t)ROWS * 512);   // bf16 [kn 512 | v 512]
  float* krtmp    = alloc((size_t)ROWS * 64);
  ushort* krbf    = (ushort*)alloc((size_t)ROWS * 32);
  float* scores   = alloc(ROWS);
  float* gpart    = alloc((size_t)ROWS * 3);
  float* bwp      = alloc(8);
  int* selidx     = (int*)alloc(1024);
  ushort* seltmp  = (ushort*)alloc((size_t)1024 * 1024);  // bf16 [sk|sv]
  ushort* wintmp  = (ushort*)alloc((size_t)ROWS * 1024);  // bf16 [wk|wv]
  ushort* attoutb = (ushort*)alloc((size_t)ROWS * 256);   // bf16 [4096][512]
  ushort* Wt_q    = (ushort*)alloc((size_t)1536 * 48);
  ushort* Wt_kv   = (ushort*)alloc((size_t)1024 * 16);
  ushort* Wt_sel  = (ushort*)alloc((size_t)2048 * 128);
  ushort* Wt_win  = (ushort*)alloc((size_t)2048 * 128);
  ushort* Wt_proj = (ushort*)alloc((size_t)256 * 256);

  // weight converts (cheap, every launch)
  wtconv_kernel<<<(1536 * 96 + 255) / 256, 256, 0, stream>>>(W_dqn, W_dqr, Wt_q, 512, 1536, 96);
  wtconv_kernel<<<(1024 * 32 + 255) / 256, 256, 0, stream>>>(W_dkn, W_dv, Wt_kv, 512, 1024, 32);
  wtconv_kernel<<<(2048 * 256 + 255) / 256, 256, 0, stream>>>(W_selk, W_selv, Wt_sel, 1536, 2048, 256);
  wtconv_kernel<<<(2048 * 256 + 255) / 256, 256, 0, stream>>>(W_wink, W_winv, Wt_win, 1536, 2048, 256);
  wtconv_kernel<<<(256 * 512 + 255) / 256, 256, 0, stream>>>(W_proj, W_proj, Wt_proj, 256, 256, 512);

  logmap_kernel<<<ROWS, 256, 0, stream>>>(x, xh, xbf);
  nq_kernel<<<ROWS, 128, 0, stream>>>(xh, W_cq, qnw, nqb);
  nkv_kernel<<<ROWS, 128, 0, stream>>>(x, W_ckv, kvnw, W_imp, b_imp, W_gate, W_kr,
                                       nkvb, scores, gpart, krtmp);
  gemm_kernel<<<dim3(32, 12), 256, 0, stream>>>(nqb, Wt_q, qtmp, nullptr, 96, 1536, 0);
  gemm_kernel<<<dim3(32, 8), 256, 0, stream>>>(nkvb, Wt_kv, kvtmp, nullptr, 32, 1024, 1);
  rope_kernel<<<ROWS, 256, 0, stream>>>(cos_f, sin_f, qtmp, krtmp, krbf);
  gate_kernel<<<1, 256, 0, stream>>>(gpart, b_gate, bwp);
  topk_kernel<<<2, 1024, 0, stream>>>(scores, selidx);
  gemm_kernel<<<dim3(8, 16), 256, 0, stream>>>(xbf, Wt_sel, seltmp, selidx, 256, 2048, 1);
  gemm_kernel<<<dim3(32, 16), 256, 0, stream>>>(xbf, Wt_win, wintmp, nullptr, 256, 2048, 1);

  dim3 fg(32, 32);
  flash_fused_kernel<<<fg, 256, 0, stream>>>(qtmp, kvtmp, krbf, seltmp, wintmp, bwp, attoutb);

  gemm_kernel<<<dim3(32, 2), 256, 0, stream>>>(attoutb, Wt_proj, out, nullptr, 512, 256, 0);
}